// Round 1
// baseline (710.356 us; speedup 1.0000x reference)
//
#include <hip/hip_runtime.h>
#include <math.h>

#define BDIM 2
#define LLEN 1024
#define DMODEL 768
#define DINNER 1536
#define DSTATE 128
#define NH 32
#define HD 48
#define CONVD 1792
#define DPROJ 3360
#define QCH 128
#define NCH 8
#define ROWS (BDIM*LLEN)

// ---- workspace layout (in floats) ----
#define SZ_ZX   ((size_t)ROWS*DPROJ)        // 6,881,280
#define SZ_XBC  ((size_t)ROWS*CONVD)        // 3,670,016
#define SZ_DT   ((size_t)ROWS*NH)           // 65,536
#define SZ_SC   ((size_t)BDIM*NH*NCH*HD*DSTATE) // 3,145,728
#define SZ_PP   ((size_t)BDIM*NH*NCH)       // 512
#define SZ_Y    ((size_t)ROWS*DINNER)       // 3,145,728
#define SZ_GO   ((size_t)ROWS*DMODEL)       // 1,572,864

#define OFF_ZX  0ull
#define OFF_XBC (OFF_ZX + SZ_ZX)
#define OFF_DT  (OFF_XBC + SZ_XBC)
#define OFF_DA  (OFF_DT + SZ_DT)
#define OFF_SC  (OFF_DA + SZ_DT)
#define OFF_HC  (OFF_SC + SZ_SC)
#define OFF_PP  (OFF_HC + SZ_SC)
#define OFF_Y   (OFF_PP + SZ_PP)
#define OFF_GO  (OFF_Y + SZ_Y)

// ================= GEMM: C[M,N] = A[M,K] * Bw[N,K]^T (fp32) =================
template<int BM, int BN, int BK, int TM, int TN, int THREADS>
__global__ __launch_bounds__(THREADS) void gemm_abt(
    const float* __restrict__ A, const float* __restrict__ Bw,
    float* __restrict__ C, int M, int N, int K) {
  __shared__ float As[BK][BM + 4];
  __shared__ float Bs[BK][BN + 4];
  const int tid = threadIdx.x;
  constexpr int NTX = BN / TN;
  const int tx = tid % NTX;
  const int ty = tid / NTX;
  const int m0 = blockIdx.y * BM;
  const int n0 = blockIdx.x * BN;

  float acc[TM][TN];
#pragma unroll
  for (int i = 0; i < TM; i++)
#pragma unroll
    for (int j = 0; j < TN; j++) acc[i][j] = 0.f;

  constexpr int KV = BK / 4;            // float4 chunks per k-row
  const int lr = tid / KV;
  const int kc = (tid % KV) * 4;

  for (int k0 = 0; k0 < K; k0 += BK) {
#pragma unroll
    for (int rr = lr; rr < BM; rr += THREADS / KV) {
      const float4 v = *(const float4*)&A[(size_t)(m0 + rr) * K + k0 + kc];
      As[kc + 0][rr] = v.x; As[kc + 1][rr] = v.y;
      As[kc + 2][rr] = v.z; As[kc + 3][rr] = v.w;
    }
#pragma unroll
    for (int rr = lr; rr < BN; rr += THREADS / KV) {
      float4 v = make_float4(0.f, 0.f, 0.f, 0.f);
      if (n0 + rr < N) v = *(const float4*)&Bw[(size_t)(n0 + rr) * K + k0 + kc];
      Bs[kc + 0][rr] = v.x; Bs[kc + 1][rr] = v.y;
      Bs[kc + 2][rr] = v.z; Bs[kc + 3][rr] = v.w;
    }
    __syncthreads();
#pragma unroll
    for (int k = 0; k < BK; k++) {
      float a[TM], bv[TN];
#pragma unroll
      for (int i = 0; i < TM; i++) a[i] = As[k][ty * TM + i];
#pragma unroll
      for (int j = 0; j < TN; j++) bv[j] = Bs[k][tx * TN + j];
#pragma unroll
      for (int i = 0; i < TM; i++)
#pragma unroll
        for (int j = 0; j < TN; j++) acc[i][j] += a[i] * bv[j];
    }
    __syncthreads();
  }

#pragma unroll
  for (int i = 0; i < TM; i++) {
    const int m = m0 + ty * TM + i;
#pragma unroll
    for (int j = 0; j < TN; j++) {
      const int n = n0 + tx * TN + j;
      if (n < N) C[(size_t)m * N + n] = acc[i][j];
    }
  }
}

// ================= conv1d (depthwise, causal, width 4) + silu + dt/dA ========
__global__ __launch_bounds__(256) void conv_dt_kernel(
    const float* __restrict__ zx, const float* __restrict__ conv_w,
    const float* __restrict__ conv_b, const float* __restrict__ dt_bias,
    const float* __restrict__ A_log,
    float* __restrict__ xbc, float* __restrict__ dtbuf, float* __restrict__ dabuf) {
  const int row = blockIdx.x;       // b*L + t
  const int t = row % LLEN;
  const int tid = threadIdx.x;
  for (int c = tid; c < CONVD; c += 256) {
    float accv = conv_b[c];
#pragma unroll
    for (int k = 0; k < 4; k++) {
      const int tt = t - 3 + k;
      if (tt >= 0)
        accv += zx[(size_t)(row - 3 + k) * DPROJ + DINNER + c] * conv_w[c * 4 + k];
    }
    const float s = accv / (1.f + expf(-accv));   // silu
    xbc[(size_t)row * CONVD + c] = s;
  }
  if (tid < NH) {
    const float v = zx[(size_t)row * DPROJ + (DPROJ - NH) + tid] + dt_bias[tid];
    const float dt = (v > 20.f) ? v : log1pf(expf(v));
    dtbuf[row * NH + tid] = dt;
    const float Aneg = -expf(A_log[tid]);
    dabuf[row * NH + tid] = expf(dt * Aneg);
  }
}

// ================= Pass A: per-chunk local state + decay product =============
__global__ __launch_bounds__(128) void scan_state_kernel(
    const float* __restrict__ xbc, const float* __restrict__ dtbuf,
    const float* __restrict__ dabuf, float* __restrict__ Sc, float* __restrict__ Pp) {
  const int c = blockIdx.x, hh = blockIdx.y, b = blockIdx.z;
  const int tid = threadIdx.x;
  const int w = tid >> 6, lane = tid & 63;
  const int nb = w * 64;
  __shared__ __align__(16) float sB[DSTATE];
  float h[64];
#pragma unroll
  for (int j = 0; j < 64; j++) h[j] = 0.f;
  float pacc = 1.f;
  const int bh = b * NH + hh;

  for (int t = c * QCH; t < (c + 1) * QCH; ++t) {
    const size_t row = (size_t)b * LLEN + t;
    sB[tid] = xbc[row * CONVD + DINNER + tid];
    __syncthreads();
    const float dAv = dabuf[row * NH + hh];
    pacc *= dAv;
    float xdt = 0.f;
    if (lane < HD) xdt = xbc[row * CONVD + hh * HD + lane] * dtbuf[row * NH + hh];
    const float4* sB4 = (const float4*)(sB + nb);
#pragma unroll
    for (int j4 = 0; j4 < 16; j4++) {
      const float4 bv = sB4[j4];
      h[j4 * 4 + 0] = h[j4 * 4 + 0] * dAv + xdt * bv.x;
      h[j4 * 4 + 1] = h[j4 * 4 + 1] * dAv + xdt * bv.y;
      h[j4 * 4 + 2] = h[j4 * 4 + 2] * dAv + xdt * bv.z;
      h[j4 * 4 + 3] = h[j4 * 4 + 3] * dAv + xdt * bv.w;
    }
    __syncthreads();
  }

  if (lane < HD) {
    float* dst = Sc + ((size_t)(bh * NCH + c)) * HD * DSTATE + (size_t)lane * DSTATE + nb;
#pragma unroll
    for (int j4 = 0; j4 < 16; j4++) {
      *(float4*)(dst + j4 * 4) =
          make_float4(h[j4 * 4], h[j4 * 4 + 1], h[j4 * 4 + 2], h[j4 * 4 + 3]);
    }
  }
  if (tid == 0) Pp[bh * NCH + c] = pacc;
}

// ================= Pass B: sequential combine across 8 chunks ================
__global__ __launch_bounds__(256) void chunk_combine_kernel(
    const float* __restrict__ Sc, const float* __restrict__ Pp,
    float* __restrict__ Hc) {
  const int bh = blockIdx.x;
  const int tid = threadIdx.x;
  for (int e = tid; e < HD * DSTATE; e += 256) {
    float hv = 0.f;
#pragma unroll
    for (int c = 0; c < NCH; c++) {
      const size_t idx = ((size_t)(bh * NCH + c)) * HD * DSTATE + e;
      Hc[idx] = hv;
      hv = hv * Pp[bh * NCH + c] + Sc[idx];
    }
  }
}

// ================= Pass C: per-chunk scan emitting y =========================
__global__ __launch_bounds__(128) void scan_y_kernel(
    const float* __restrict__ xbc, const float* __restrict__ dtbuf,
    const float* __restrict__ dabuf, const float* __restrict__ Hc,
    float* __restrict__ y) {
  const int c = blockIdx.x, hh = blockIdx.y, b = blockIdx.z;
  const int tid = threadIdx.x;
  const int w = tid >> 6, lane = tid & 63;
  const int nb = w * 64;
  __shared__ __align__(16) float sB[DSTATE];
  __shared__ __align__(16) float sC[DSTATE];
  __shared__ float sY[2][HD];
  const int bh = b * NH + hh;

  float h[64];
  if (lane < HD) {
    const float* src = Hc + ((size_t)(bh * NCH + c)) * HD * DSTATE + (size_t)lane * DSTATE + nb;
#pragma unroll
    for (int j4 = 0; j4 < 16; j4++) {
      const float4 v = *(const float4*)(src + j4 * 4);
      h[j4 * 4 + 0] = v.x; h[j4 * 4 + 1] = v.y;
      h[j4 * 4 + 2] = v.z; h[j4 * 4 + 3] = v.w;
    }
  } else {
#pragma unroll
    for (int j = 0; j < 64; j++) h[j] = 0.f;
  }

  for (int t = c * QCH; t < (c + 1) * QCH; ++t) {
    const size_t row = (size_t)b * LLEN + t;
    sB[tid] = xbc[row * CONVD + DINNER + tid];
    sC[tid] = xbc[row * CONVD + DINNER + DSTATE + tid];
    __syncthreads();
    const float dAv = dabuf[row * NH + hh];
    float xdt = 0.f;
    if (lane < HD) xdt = xbc[row * CONVD + hh * HD + lane] * dtbuf[row * NH + hh];
    float yp = 0.f;
    const float4* sB4 = (const float4*)(sB + nb);
    const float4* sC4 = (const float4*)(sC + nb);
#pragma unroll
    for (int j4 = 0; j4 < 16; j4++) {
      const float4 bv = sB4[j4];
      const float4 cv = sC4[j4];
      h[j4 * 4 + 0] = h[j4 * 4 + 0] * dAv + xdt * bv.x;
      h[j4 * 4 + 1] = h[j4 * 4 + 1] * dAv + xdt * bv.y;
      h[j4 * 4 + 2] = h[j4 * 4 + 2] * dAv + xdt * bv.z;
      h[j4 * 4 + 3] = h[j4 * 4 + 3] * dAv + xdt * bv.w;
      yp += h[j4 * 4 + 0] * cv.x;
      yp += h[j4 * 4 + 1] * cv.y;
      yp += h[j4 * 4 + 2] * cv.z;
      yp += h[j4 * 4 + 3] * cv.w;
    }
    if (lane < HD) sY[w][lane] = yp;
    __syncthreads();
    if (w == 0 && lane < HD)
      y[row * DINNER + hh * HD + lane] = sY[0][lane] + sY[1][lane];
  }
}

// ================= gate (silu(z)) + RMSNorm over 1536 ========================
__global__ __launch_bounds__(256) void gate_rms_kernel(
    const float* __restrict__ zx, const float* __restrict__ xbc,
    const float* __restrict__ Dv, const float* __restrict__ rms_w,
    float* __restrict__ y) {
  const int row = blockIdx.x;
  const int tid = threadIdx.x;
  __shared__ float sred[4];
  float g[6];
  float ss = 0.f;
#pragma unroll
  for (int i = 0; i < 6; i++) {
    const int e = tid + i * 256;
    const float yv = y[(size_t)row * DINNER + e] + Dv[e / HD] * xbc[(size_t)row * CONVD + e];
    const float z = zx[(size_t)row * DPROJ + e];
    const float gv = yv * (z / (1.f + expf(-z)));
    g[i] = gv;
    ss += gv * gv;
  }
#pragma unroll
  for (int off = 32; off; off >>= 1) ss += __shfl_down(ss, off, 64);
  if ((tid & 63) == 0) sred[tid >> 6] = ss;
  __syncthreads();
  const float tot = sred[0] + sred[1] + sred[2] + sred[3];
  const float scale = rsqrtf(tot / DINNER + 1e-5f);
#pragma unroll
  for (int i = 0; i < 6; i++) {
    const int e = tid + i * 256;
    y[(size_t)row * DINNER + e] = g[i] * scale * rms_w[e];
  }
}

// ================= residual + LayerNorm over 768 =============================
__global__ __launch_bounds__(256) void resid_ln_kernel(
    const float* __restrict__ go, const float* __restrict__ x,
    const float* __restrict__ ln_w, const float* __restrict__ ln_b,
    float* __restrict__ out) {
  const int row = blockIdx.x;
  const int tid = threadIdx.x;
  __shared__ float sred[4];
  __shared__ float sred2[4];
  float r[3];
  float s = 0.f;
#pragma unroll
  for (int i = 0; i < 3; i++) {
    const int e = tid + i * 256;
    r[i] = go[(size_t)row * DMODEL + e] + x[(size_t)row * DMODEL + e];
    s += r[i];
  }
#pragma unroll
  for (int off = 32; off; off >>= 1) s += __shfl_down(s, off, 64);
  if ((tid & 63) == 0) sred[tid >> 6] = s;
  __syncthreads();
  const float mu = (sred[0] + sred[1] + sred[2] + sred[3]) * (1.f / DMODEL);
  float s2 = 0.f;
#pragma unroll
  for (int i = 0; i < 3; i++) {
    const float d = r[i] - mu;
    s2 += d * d;
  }
#pragma unroll
  for (int off = 32; off; off >>= 1) s2 += __shfl_down(s2, off, 64);
  if ((tid & 63) == 0) sred2[tid >> 6] = s2;
  __syncthreads();
  const float var = (sred2[0] + sred2[1] + sred2[2] + sred2[3]) * (1.f / DMODEL);
  const float inv = rsqrtf(var + 1e-5f);
#pragma unroll
  for (int i = 0; i < 3; i++) {
    const int e = tid + i * 256;
    out[(size_t)row * DMODEL + e] = (r[i] - mu) * inv * ln_w[e] + ln_b[e];
  }
}

// ================= launch ====================================================
extern "C" void kernel_launch(void* const* d_in, const int* in_sizes, int n_in,
                              void* d_out, int out_size, void* d_ws, size_t ws_size,
                              hipStream_t stream) {
  const float* x          = (const float*)d_in[0];
  const float* in_proj_w  = (const float*)d_in[1];
  const float* conv_w     = (const float*)d_in[2];
  const float* conv_b     = (const float*)d_in[3];
  const float* dt_bias    = (const float*)d_in[4];
  const float* A_log      = (const float*)d_in[5];
  const float* Dv         = (const float*)d_in[6];
  const float* rms_w      = (const float*)d_in[7];
  const float* out_proj_w = (const float*)d_in[8];
  const float* ln_w       = (const float*)d_in[9];
  const float* ln_b       = (const float*)d_in[10];
  float* out = (float*)d_out;
  float* ws  = (float*)d_ws;

  float* zx   = ws + OFF_ZX;
  float* xbc  = ws + OFF_XBC;
  float* dtb  = ws + OFF_DT;
  float* dab  = ws + OFF_DA;
  float* Sc   = ws + OFF_SC;
  float* Hc   = ws + OFF_HC;
  float* Pp   = ws + OFF_PP;
  float* ybuf = ws + OFF_Y;
  float* go   = ws + OFF_GO;

  // 1) in_proj: zx[2048,3360] = x[2048,768] @ in_proj_w[3360,768]^T
  gemm_abt<128, 128, 8, 8, 8, 256>
      <<<dim3((DPROJ + 127) / 128, ROWS / 128), 256, 0, stream>>>(
          x, in_proj_w, zx, ROWS, DPROJ, DMODEL);

  // 2) conv + silu + dt/dA
  conv_dt_kernel<<<ROWS, 256, 0, stream>>>(zx, conv_w, conv_b, dt_bias, A_log,
                                           xbc, dtb, dab);

  // 3) chunked scan
  scan_state_kernel<<<dim3(NCH, NH, BDIM), 128, 0, stream>>>(xbc, dtb, dab, Sc, Pp);
  chunk_combine_kernel<<<BDIM * NH, 256, 0, stream>>>(Sc, Pp, Hc);
  scan_y_kernel<<<dim3(NCH, NH, BDIM), 128, 0, stream>>>(xbc, dtb, dab, Hc, ybuf);

  // 4) gate + RMSNorm (in-place on ybuf)
  gate_rms_kernel<<<ROWS, 256, 0, stream>>>(zx, xbc, Dv, rms_w, ybuf);

  // 5) out_proj: go[2048,768] = ybuf[2048,1536] @ out_proj_w[768,1536]^T
  gemm_abt<64, 64, 16, 4, 4, 256>
      <<<dim3(DMODEL / 64, ROWS / 64), 256, 0, stream>>>(
          ybuf, out_proj_w, go, ROWS, DMODEL, DINNER);

  // 6) residual + LayerNorm
  resid_ln_kernel<<<ROWS, 256, 0, stream>>>(go, x, ln_w, ln_b, out);
}

// Round 2
// 511.782 us; speedup vs baseline: 1.3880x; 1.3880x over previous
//
#include <hip/hip_runtime.h>
#include <math.h>

#define BDIM 2
#define LLEN 1024
#define DMODEL 768
#define DINNER 1536
#define DSTATE 128
#define NH 32
#define HD 48
#define CONVD 1792
#define DPROJ 3360
#define DPROJP 3456   // padded to 27*128 for the MFMA GEMM
#define QCH 128
#define NCH 8
#define ROWS (BDIM*LLEN)

typedef unsigned short ushort_t;
typedef __attribute__((ext_vector_type(8))) short short8v;   // 8 bf16 (4 VGPRs)
typedef __attribute__((ext_vector_type(4))) float floatx4;

// ---- workspace layout (in floats) ----
// zx  [2048][3456] fp32          0          .. 7,077,888
// xbc [2048][1792] fp32          7,077,888  .. 10,747,904
// dt  [2048][32]                 10,747,904 .. 10,813,440
// da  [2048][32]                 10,813,440 .. 10,878,976
// Sc  [64][8][48][128] fp32      10,878,976 .. 14,024,704   (combine runs in-place)
// y   [2048][1536] fp32          14,024,704 .. 17,170,432
// Pp  [512]                      17,170,432 .. 17,170,944
// aliases:
//   x_bf16   (1,572,864 u16) + ipw_bf16 (2,654,208 u16) live in the y region (GEMM1 phase)
//   y_bf16   (3,145,728 u16) + opw_bf16 (1,179,648 u16) live in the Sc region (GEMM2 phase)
//   go [2048][768] fp32 lives in the zx region (post gate_rms)
#define OFF_ZX  0ull
#define OFF_XBC (OFF_ZX + (size_t)ROWS*DPROJP)
#define OFF_DT  (OFF_XBC + (size_t)ROWS*CONVD)
#define OFF_DA  (OFF_DT + (size_t)ROWS*NH)
#define OFF_SC  (OFF_DA + (size_t)ROWS*NH)
#define OFF_Y   (OFF_SC + (size_t)BDIM*NH*NCH*HD*DSTATE)
#define OFF_PP  (OFF_Y + (size_t)ROWS*DINNER)

__device__ __forceinline__ ushort_t f2bf(float f) {
  union { float f; unsigned int u; } v; v.f = f;
  return (ushort_t)((v.u + 0x7FFFu + ((v.u >> 16) & 1u)) >> 16);
}

#define GLOAD_LDS16(gptr, lptr) \
  __builtin_amdgcn_global_load_lds( \
      (const __attribute__((address_space(1))) void*)(gptr), \
      (__attribute__((address_space(3))) void*)(lptr), 16, 0, 0)

// ================= f32 -> bf16 conversion (8 elems/thread) ===================
__global__ __launch_bounds__(256) void convert_bf16_kernel(
    const float* __restrict__ in, ushort_t* __restrict__ out, int n8) {
  const int i = blockIdx.x * 256 + threadIdx.x;
  if (i >= n8) return;
  const float4 a = ((const float4*)in)[i * 2];
  const float4 b = ((const float4*)in)[i * 2 + 1];
  short8v o;
  o[0] = (short)f2bf(a.x); o[1] = (short)f2bf(a.y);
  o[2] = (short)f2bf(a.z); o[3] = (short)f2bf(a.w);
  o[4] = (short)f2bf(b.x); o[5] = (short)f2bf(b.y);
  o[6] = (short)f2bf(b.z); o[7] = (short)f2bf(b.w);
  *(short8v*)(out + (size_t)i * 8) = o;
}

// in_proj_w [3360][768] -> bf16 padded to [3456][768] (zero rows)
__global__ __launch_bounds__(256) void convert_wpad_kernel(
    const float* __restrict__ w, ushort_t* __restrict__ out) {
  const int i = blockIdx.x * 256 + threadIdx.x;   // i8 over 3456*96
  if (i >= DPROJP * (DMODEL / 8)) return;
  const int row = i / (DMODEL / 8);
  short8v o;
  if (row < DPROJ) {
    const float4 a = ((const float4*)w)[i * 2];
    const float4 b = ((const float4*)w)[i * 2 + 1];
    o[0] = (short)f2bf(a.x); o[1] = (short)f2bf(a.y);
    o[2] = (short)f2bf(a.z); o[3] = (short)f2bf(a.w);
    o[4] = (short)f2bf(b.x); o[5] = (short)f2bf(b.y);
    o[6] = (short)f2bf(b.z); o[7] = (short)f2bf(b.w);
  } else {
    for (int j = 0; j < 8; j++) o[j] = 0;
  }
  *(short8v*)(out + (size_t)i * 8) = o;
}

// ============ bf16 MFMA GEMM (m97 structure): C[M,N] = A[M,K] x B[N,K]^T =====
// 128x128 tile, BK=32, 4 waves (2x2 of 64x64), global_load_lds width-16.
__global__ __launch_bounds__(256) void gemm_bf16(
    const ushort_t* __restrict__ A, const ushort_t* __restrict__ B,
    float* __restrict__ C, int M, int N, int K) {
  __shared__ __align__(16) ushort_t As[128 * 32];
  __shared__ __align__(16) ushort_t Bs[128 * 32];
  const int tid = threadIdx.x;
  const int lane = tid & 63;
  const int w = tid >> 6;
  const int wm = (w >> 1) * 64, wn = (w & 1) * 64;
  const int m0 = blockIdx.y * 128, n0 = blockIdx.x * 128;

  floatx4 acc[4][4];
#pragma unroll
  for (int i = 0; i < 4; i++)
#pragma unroll
    for (int j = 0; j < 4; j++) acc[i][j] = (floatx4){0.f, 0.f, 0.f, 0.f};

  const int srow = tid >> 2;       // 0..63
  const int skc = (tid & 3) * 8;   // 0,8,16,24

  const int kk = (lane >> 4) * 8;  // fragment k-offset
  const int fr = lane & 15;        // fragment row/col

  for (int k0 = 0; k0 < K; k0 += 32) {
#pragma unroll
    for (int i = 0; i < 2; i++) {
      GLOAD_LDS16(A + (size_t)(m0 + i * 64 + srow) * K + k0 + skc,
                  As + (i * 64 + srow) * 32 + skc);
      GLOAD_LDS16(B + (size_t)(n0 + i * 64 + srow) * K + k0 + skc,
                  Bs + (i * 64 + srow) * 32 + skc);
    }
    __syncthreads();   // drains vmcnt(0): staged data visible
    short8v a[4], bv[4];
#pragma unroll
    for (int mr = 0; mr < 4; mr++)
      a[mr] = *(const short8v*)(As + (wm + mr * 16 + fr) * 32 + kk);
#pragma unroll
    for (int nc = 0; nc < 4; nc++)
      bv[nc] = *(const short8v*)(Bs + (wn + nc * 16 + fr) * 32 + kk);
#pragma unroll
    for (int mr = 0; mr < 4; mr++)
#pragma unroll
      for (int nc = 0; nc < 4; nc++)
        acc[mr][nc] = __builtin_amdgcn_mfma_f32_16x16x32_bf16(
            a[mr], bv[nc], acc[mr][nc], 0, 0, 0);
    __syncthreads();   // LDS reads done before next stage overwrites
  }

  const int crow = (lane >> 4) * 4;
#pragma unroll
  for (int mr = 0; mr < 4; mr++)
#pragma unroll
    for (int nc = 0; nc < 4; nc++)
#pragma unroll
      for (int j = 0; j < 4; j++)
        C[(size_t)(m0 + wm + mr * 16 + crow + j) * N + n0 + wn + nc * 16 + fr] =
            acc[mr][nc][j];
}

// ================= conv1d (depthwise, causal, width 4) + silu + dt/dA ========
__global__ __launch_bounds__(256) void conv_dt_kernel(
    const float* __restrict__ zx, const float* __restrict__ conv_w,
    const float* __restrict__ conv_b, const float* __restrict__ dt_bias,
    const float* __restrict__ A_log,
    float* __restrict__ xbc, float* __restrict__ dtbuf, float* __restrict__ dabuf) {
  const int row = blockIdx.x;       // b*L + t
  const int t = row % LLEN;
  const int tid = threadIdx.x;
  for (int c = tid; c < CONVD; c += 256) {
    float accv = conv_b[c];
#pragma unroll
    for (int k = 0; k < 4; k++) {
      const int tt = t - 3 + k;
      if (tt >= 0)
        accv += zx[(size_t)(row - 3 + k) * DPROJP + DINNER + c] * conv_w[c * 4 + k];
    }
    const float s = accv / (1.f + expf(-accv));   // silu
    xbc[(size_t)row * CONVD + c] = s;
  }
  if (tid < NH) {
    const float v = zx[(size_t)row * DPROJP + (DPROJ - NH) + tid] + dt_bias[tid];
    const float dt = (v > 20.f) ? v : log1pf(expf(v));
    dtbuf[row * NH + tid] = dt;
    const float Aneg = -expf(A_log[tid]);
    dabuf[row * NH + tid] = expf(dt * Aneg);
  }
}

// ================= Pass A: per-chunk local state + decay product =============
__global__ __launch_bounds__(128) void scan_state_kernel(
    const float* __restrict__ xbc, const float* __restrict__ dtbuf,
    const float* __restrict__ dabuf, float* __restrict__ Sc, float* __restrict__ Pp) {
  const int c = blockIdx.x, hh = blockIdx.y, b = blockIdx.z;
  const int tid = threadIdx.x;
  const int w = tid >> 6, lane = tid & 63;
  const int nb = w * 64;
  __shared__ __align__(16) float sB[DSTATE];
  float h[64];
#pragma unroll
  for (int j = 0; j < 64; j++) h[j] = 0.f;
  float pacc = 1.f;
  const int bh = b * NH + hh;

  for (int t = c * QCH; t < (c + 1) * QCH; ++t) {
    const size_t row = (size_t)b * LLEN + t;
    sB[tid] = xbc[row * CONVD + DINNER + tid];
    __syncthreads();
    const float dAv = dabuf[row * NH + hh];
    pacc *= dAv;
    float xdt = 0.f;
    if (lane < HD) xdt = xbc[row * CONVD + hh * HD + lane] * dtbuf[row * NH + hh];
    const float4* sB4 = (const float4*)(sB + nb);
#pragma unroll
    for (int j4 = 0; j4 < 16; j4++) {
      const float4 bvv = sB4[j4];
      h[j4 * 4 + 0] = h[j4 * 4 + 0] * dAv + xdt * bvv.x;
      h[j4 * 4 + 1] = h[j4 * 4 + 1] * dAv + xdt * bvv.y;
      h[j4 * 4 + 2] = h[j4 * 4 + 2] * dAv + xdt * bvv.z;
      h[j4 * 4 + 3] = h[j4 * 4 + 3] * dAv + xdt * bvv.w;
    }
    __syncthreads();
  }

  if (lane < HD) {
    float* dst = Sc + ((size_t)(bh * NCH + c)) * HD * DSTATE + (size_t)lane * DSTATE + nb;
#pragma unroll
    for (int j4 = 0; j4 < 16; j4++) {
      *(float4*)(dst + j4 * 4) =
          make_float4(h[j4 * 4], h[j4 * 4 + 1], h[j4 * 4 + 2], h[j4 * 4 + 3]);
    }
  }
  if (tid == 0) Pp[bh * NCH + c] = pacc;
}

// ===== Pass B: sequential combine across 8 chunks (in-place: Sc -> Hc) =======
__global__ __launch_bounds__(256) void chunk_combine_kernel(
    float* __restrict__ Sc, const float* __restrict__ Pp) {
  const int bh = blockIdx.x;
  const int tid = threadIdx.x;
  for (int e = tid; e < HD * DSTATE; e += 256) {
    float hv = 0.f;
#pragma unroll
    for (int c = 0; c < NCH; c++) {
      const size_t idx = ((size_t)(bh * NCH + c)) * HD * DSTATE + e;
      const float sv = Sc[idx];
      Sc[idx] = hv;                 // Hc: state entering chunk c
      hv = hv * Pp[bh * NCH + c] + sv;
    }
  }
}

// ================= Pass C: per-chunk scan emitting y =========================
__global__ __launch_bounds__(128) void scan_y_kernel(
    const float* __restrict__ xbc, const float* __restrict__ dtbuf,
    const float* __restrict__ dabuf, const float* __restrict__ Hc,
    float* __restrict__ y) {
  const int c = blockIdx.x, hh = blockIdx.y, b = blockIdx.z;
  const int tid = threadIdx.x;
  const int w = tid >> 6, lane = tid & 63;
  const int nb = w * 64;
  __shared__ __align__(16) float sB[DSTATE];
  __shared__ __align__(16) float sC[DSTATE];
  __shared__ float sY[2][HD];
  const int bh = b * NH + hh;

  float h[64];
  if (lane < HD) {
    const float* src = Hc + ((size_t)(bh * NCH + c)) * HD * DSTATE + (size_t)lane * DSTATE + nb;
#pragma unroll
    for (int j4 = 0; j4 < 16; j4++) {
      const float4 v = *(const float4*)(src + j4 * 4);
      h[j4 * 4 + 0] = v.x; h[j4 * 4 + 1] = v.y;
      h[j4 * 4 + 2] = v.z; h[j4 * 4 + 3] = v.w;
    }
  } else {
#pragma unroll
    for (int j = 0; j < 64; j++) h[j] = 0.f;
  }

  for (int t = c * QCH; t < (c + 1) * QCH; ++t) {
    const size_t row = (size_t)b * LLEN + t;
    sB[tid] = xbc[row * CONVD + DINNER + tid];
    sC[tid] = xbc[row * CONVD + DINNER + DSTATE + tid];
    __syncthreads();
    const float dAv = dabuf[row * NH + hh];
    float xdt = 0.f;
    if (lane < HD) xdt = xbc[row * CONVD + hh * HD + lane] * dtbuf[row * NH + hh];
    float yp = 0.f;
    const float4* sB4 = (const float4*)(sB + nb);
    const float4* sC4 = (const float4*)(sC + nb);
#pragma unroll
    for (int j4 = 0; j4 < 16; j4++) {
      const float4 bvv = sB4[j4];
      const float4 cvv = sC4[j4];
      h[j4 * 4 + 0] = h[j4 * 4 + 0] * dAv + xdt * bvv.x;
      h[j4 * 4 + 1] = h[j4 * 4 + 1] * dAv + xdt * bvv.y;
      h[j4 * 4 + 2] = h[j4 * 4 + 2] * dAv + xdt * bvv.z;
      h[j4 * 4 + 3] = h[j4 * 4 + 3] * dAv + xdt * bvv.w;
      yp += h[j4 * 4 + 0] * cvv.x;
      yp += h[j4 * 4 + 1] * cvv.y;
      yp += h[j4 * 4 + 2] * cvv.z;
      yp += h[j4 * 4 + 3] * cvv.w;
    }
    if (lane < HD) sY[w][lane] = yp;
    __syncthreads();
    if (w == 0 && lane < HD)
      y[row * DINNER + hh * HD + lane] = sY[0][lane] + sY[1][lane];
  }
}

// ===== gate (silu(z)) + RMSNorm over 1536, emit bf16 for out_proj GEMM =======
__global__ __launch_bounds__(256) void gate_rms_kernel(
    const float* __restrict__ zx, const float* __restrict__ xbc,
    const float* __restrict__ Dv, const float* __restrict__ rms_w,
    const float* __restrict__ y, ushort_t* __restrict__ ybf) {
  const int row = blockIdx.x;
  const int tid = threadIdx.x;
  __shared__ float sred[4];
  float g[6];
  float ss = 0.f;
#pragma unroll
  for (int i = 0; i < 6; i++) {
    const int e = tid + i * 256;
    const float yv = y[(size_t)row * DINNER + e] + Dv[e / HD] * xbc[(size_t)row * CONVD + e];
    const float z = zx[(size_t)row * DPROJP + e];
    const float gv = yv * (z / (1.f + expf(-z)));
    g[i] = gv;
    ss += gv * gv;
  }
#pragma unroll
  for (int off = 32; off; off >>= 1) ss += __shfl_down(ss, off, 64);
  if ((tid & 63) == 0) sred[tid >> 6] = ss;
  __syncthreads();
  const float tot = sred[0] + sred[1] + sred[2] + sred[3];
  const float scale = rsqrtf(tot / DINNER + 1e-5f);
#pragma unroll
  for (int i = 0; i < 6; i++) {
    const int e = tid + i * 256;
    ybf[(size_t)row * DINNER + e] = f2bf(g[i] * scale * rms_w[e]);
  }
}

// ================= residual + LayerNorm over 768 =============================
__global__ __launch_bounds__(256) void resid_ln_kernel(
    const float* __restrict__ go, const float* __restrict__ x,
    const float* __restrict__ ln_w, const float* __restrict__ ln_b,
    float* __restrict__ out) {
  const int row = blockIdx.x;
  const int tid = threadIdx.x;
  __shared__ float sred[4];
  __shared__ float sred2[4];
  float r[3];
  float s = 0.f;
#pragma unroll
  for (int i = 0; i < 3; i++) {
    const int e = tid + i * 256;
    r[i] = go[(size_t)row * DMODEL + e] + x[(size_t)row * DMODEL + e];
    s += r[i];
  }
#pragma unroll
  for (int off = 32; off; off >>= 1) s += __shfl_down(s, off, 64);
  if ((tid & 63) == 0) sred[tid >> 6] = s;
  __syncthreads();
  const float mu = (sred[0] + sred[1] + sred[2] + sred[3]) * (1.f / DMODEL);
  float s2 = 0.f;
#pragma unroll
  for (int i = 0; i < 3; i++) {
    const float d = r[i] - mu;
    s2 += d * d;
  }
#pragma unroll
  for (int off = 32; off; off >>= 1) s2 += __shfl_down(s2, off, 64);
  if ((tid & 63) == 0) sred2[tid >> 6] = s2;
  __syncthreads();
  const float var = (sred2[0] + sred2[1] + sred2[2] + sred2[3]) * (1.f / DMODEL);
  const float inv = rsqrtf(var + 1e-5f);
#pragma unroll
  for (int i = 0; i < 3; i++) {
    const int e = tid + i * 256;
    out[(size_t)row * DMODEL + e] = (r[i] - mu) * inv * ln_w[e] + ln_b[e];
  }
}

// ================= launch ====================================================
extern "C" void kernel_launch(void* const* d_in, const int* in_sizes, int n_in,
                              void* d_out, int out_size, void* d_ws, size_t ws_size,
                              hipStream_t stream) {
  const float* x          = (const float*)d_in[0];
  const float* in_proj_w  = (const float*)d_in[1];
  const float* conv_w     = (const float*)d_in[2];
  const float* conv_b     = (const float*)d_in[3];
  const float* dt_bias    = (const float*)d_in[4];
  const float* A_log      = (const float*)d_in[5];
  const float* Dv         = (const float*)d_in[6];
  const float* rms_w      = (const float*)d_in[7];
  const float* out_proj_w = (const float*)d_in[8];
  const float* ln_w       = (const float*)d_in[9];
  const float* ln_b       = (const float*)d_in[10];
  float* out = (float*)d_out;
  float* ws  = (float*)d_ws;

  float* zx   = ws + OFF_ZX;
  float* xbc  = ws + OFF_XBC;
  float* dtb  = ws + OFF_DT;
  float* dab  = ws + OFF_DA;
  float* Sc   = ws + OFF_SC;          // also Hc after in-place combine
  float* ybuf = ws + OFF_Y;
  float* Pp   = ws + OFF_PP;

  // aliased staging buffers
  ushort_t* xbf   = (ushort_t*)(ws + OFF_Y);                 // GEMM1 phase
  ushort_t* ipwbf = (ushort_t*)(ws + OFF_Y + 786432);        // GEMM1 phase
  ushort_t* ybf   = (ushort_t*)(ws + OFF_SC);                // GEMM2 phase
  ushort_t* opwbf = (ushort_t*)(ws + OFF_SC + 1572864);      // GEMM2 phase
  float*    go    = ws + OFF_ZX;                             // GEMM2 output

  // 0) convert x and in_proj_w (padded) to bf16
  convert_bf16_kernel<<<(ROWS * DMODEL / 8 + 255) / 256, 256, 0, stream>>>(
      x, xbf, ROWS * DMODEL / 8);
  convert_wpad_kernel<<<(DPROJP * DMODEL / 8 + 255) / 256, 256, 0, stream>>>(
      in_proj_w, ipwbf);

  // 1) in_proj: zx[2048,3456] = x[2048,768] @ ipw[3456,768]^T  (bf16 MFMA)
  gemm_bf16<<<dim3(DPROJP / 128, ROWS / 128), 256, 0, stream>>>(
      xbf, ipwbf, zx, ROWS, DPROJP, DMODEL);

  // 2) conv + silu + dt/dA
  conv_dt_kernel<<<ROWS, 256, 0, stream>>>(zx, conv_w, conv_b, dt_bias, A_log,
                                           xbc, dtb, dab);

  // 3) chunked scan
  scan_state_kernel<<<dim3(NCH, NH, BDIM), 128, 0, stream>>>(xbc, dtb, dab, Sc, Pp);
  chunk_combine_kernel<<<BDIM * NH, 256, 0, stream>>>(Sc, Pp);
  scan_y_kernel<<<dim3(NCH, NH, BDIM), 128, 0, stream>>>(xbc, dtb, dab, Sc, ybuf);

  // 4) gate + RMSNorm -> bf16
  gate_rms_kernel<<<ROWS, 256, 0, stream>>>(zx, xbc, Dv, rms_w, ybuf, ybf);

  // 5) convert out_proj_w, then out_proj GEMM: go = ybf @ opw^T
  convert_bf16_kernel<<<(DMODEL * DINNER / 8 + 255) / 256, 256, 0, stream>>>(
      out_proj_w, opwbf, DMODEL * DINNER / 8);
  gemm_bf16<<<dim3(DMODEL / 128, ROWS / 128), 256, 0, stream>>>(
      ybf, opwbf, go, ROWS, DMODEL, DINNER);

  // 6) residual + LayerNorm
  resid_ln_kernel<<<ROWS, 256, 0, stream>>>(go, x, ln_w, ln_b, out);
}

// Round 7
// 256.161 us; speedup vs baseline: 2.7731x; 1.9979x over previous
//
#include <hip/hip_runtime.h>
#include <math.h>

#define BDIM 2
#define LLEN 1024
#define DMODEL 768
#define DINNER 1536
#define DSTATE 128
#define NH 32
#define HD 48
#define CONVD 1792
#define DPROJ 3360
#define DPROJP 3456   // padded to 27*128 for the MFMA GEMM
#define QCH 128
#define NCH 8
#define ROWS (BDIM*LLEN)

typedef unsigned short ushort_t;
typedef __attribute__((ext_vector_type(4))) short short4v;
typedef __attribute__((ext_vector_type(8))) short short8v;   // 8 bf16 (4 VGPRs)
typedef __attribute__((ext_vector_type(4))) float floatx4;

// ---- workspace layout (floats) ----
#define OFF_ZX   0ull                                   // zx [2048][3456]; go aliases later
#define OFF_XBC  (OFF_ZX  + (size_t)ROWS*DPROJP)        // xbc [2048][1792]
#define OFF_DT   (OFF_XBC + (size_t)ROWS*CONVD)         // dt [2048][32]
#define OFF_LA   (OFF_DT  + (size_t)ROWS*NH)            // la2 [2048][32] (A*cumsum(dt)*log2e)
#define OFF_SC   (OFF_LA  + (size_t)ROWS*NH)            // Sc [64][8][48][128]; ybf/opwbf alias later
#define OFF_Y    (OFF_SC  + (size_t)BDIM*NH*NCH*HD*DSTATE) // y [2048][1536]; xbf/ipwbf alias earlier
#define OFF_PP   (OFF_Y   + (size_t)ROWS*DINNER)        // Pp [512] (pad 1024)
#define OFF_CBT  (OFF_PP  + 1024ull)                    // CBt [16][128][128] fp32
#define OFF_CBF  (OFF_CBT + 262144ull)                  // Cbf  [16][128][128] bf16 (131072 f)
#define OFF_BBF  (OFF_CBF + 131072ull)                  // Bbf  bf16
#define OFF_BTBF (OFF_BBF + 131072ull)                  // BTbf bf16 [16][n=128][t=128]
#define OFF_XPT  (OFF_BTBF+ 131072ull)                  // XpT [2][8][32][48][128] bf16 (1572864 f)
// total = 19,399,680 floats (~74 MB)

__device__ __forceinline__ ushort_t f2bf(float f) {
  union { float f; unsigned int u; } v; v.f = f;
  return (ushort_t)((v.u + 0x7FFFu + ((v.u >> 16) & 1u)) >> 16);
}
__device__ __forceinline__ float bf2f(short s) {
  union { unsigned int u; float f; } v; v.u = ((unsigned int)(ushort_t)s) << 16;
  return v.f;
}

#define GLOAD_LDS16(gptr, lptr) \
  __builtin_amdgcn_global_load_lds( \
      (const __attribute__((address_space(1))) void*)(gptr), \
      (__attribute__((address_space(3))) void*)(lptr), 16, 0, 0)

// ================= f32 -> bf16 conversion (8 elems/thread) ===================
__global__ __launch_bounds__(256) void convert_bf16_kernel(
    const float* __restrict__ in, ushort_t* __restrict__ out, int n8) {
  const int i = blockIdx.x * 256 + threadIdx.x;
  if (i >= n8) return;
  const float4 a = ((const float4*)in)[i * 2];
  const float4 b = ((const float4*)in)[i * 2 + 1];
  short8v o;
  o[0] = (short)f2bf(a.x); o[1] = (short)f2bf(a.y);
  o[2] = (short)f2bf(a.z); o[3] = (short)f2bf(a.w);
  o[4] = (short)f2bf(b.x); o[5] = (short)f2bf(b.y);
  o[6] = (short)f2bf(b.z); o[7] = (short)f2bf(b.w);
  *(short8v*)(out + (size_t)i * 8) = o;
}

// in_proj_w [3360][768] -> bf16 padded to [3456][768] (zero rows)
__global__ __launch_bounds__(256) void convert_wpad_kernel(
    const float* __restrict__ w, ushort_t* __restrict__ out) {
  const int i = blockIdx.x * 256 + threadIdx.x;
  if (i >= DPROJP * (DMODEL / 8)) return;
  const int row = i / (DMODEL / 8);
  short8v o;
  if (row < DPROJ) {
    const float4 a = ((const float4*)w)[i * 2];
    const float4 b = ((const float4*)w)[i * 2 + 1];
    o[0] = (short)f2bf(a.x); o[1] = (short)f2bf(a.y);
    o[2] = (short)f2bf(a.z); o[3] = (short)f2bf(a.w);
    o[4] = (short)f2bf(b.x); o[5] = (short)f2bf(b.y);
    o[6] = (short)f2bf(b.z); o[7] = (short)f2bf(b.w);
  } else {
    for (int j = 0; j < 8; j++) o[j] = 0;
  }
  *(short8v*)(out + (size_t)i * 8) = o;
}

// ============ bf16 MFMA GEMM (m97 structure): C[M,N] = A[M,K] x B[N,K]^T =====
__global__ __launch_bounds__(256) void gemm_bf16(
    const ushort_t* __restrict__ A, const ushort_t* __restrict__ B,
    float* __restrict__ C, int M, int N, int K) {
  __shared__ __align__(16) ushort_t As[128 * 32];
  __shared__ __align__(16) ushort_t Bs[128 * 32];
  const int tid = threadIdx.x;
  const int lane = tid & 63;
  const int w = tid >> 6;
  const int wm = (w >> 1) * 64, wn = (w & 1) * 64;
  const int m0 = blockIdx.y * 128, n0 = blockIdx.x * 128;

  floatx4 acc[4][4];
#pragma unroll
  for (int i = 0; i < 4; i++)
#pragma unroll
    for (int j = 0; j < 4; j++) acc[i][j] = (floatx4){0.f, 0.f, 0.f, 0.f};

  const int srow = tid >> 2;
  const int skc = (tid & 3) * 8;
  const int kk = (lane >> 4) * 8;
  const int fr = lane & 15;

  for (int k0 = 0; k0 < K; k0 += 32) {
#pragma unroll
    for (int i = 0; i < 2; i++) {
      GLOAD_LDS16(A + (size_t)(m0 + i * 64 + srow) * K + k0 + skc,
                  As + (i * 64 + srow) * 32 + skc);
      GLOAD_LDS16(B + (size_t)(n0 + i * 64 + srow) * K + k0 + skc,
                  Bs + (i * 64 + srow) * 32 + skc);
    }
    __syncthreads();
    short8v a[4], bv[4];
#pragma unroll
    for (int mr = 0; mr < 4; mr++)
      a[mr] = *(const short8v*)(As + (wm + mr * 16 + fr) * 32 + kk);
#pragma unroll
    for (int nc = 0; nc < 4; nc++)
      bv[nc] = *(const short8v*)(Bs + (wn + nc * 16 + fr) * 32 + kk);
#pragma unroll
    for (int mr = 0; mr < 4; mr++)
#pragma unroll
      for (int nc = 0; nc < 4; nc++)
        acc[mr][nc] = __builtin_amdgcn_mfma_f32_16x16x32_bf16(
            a[mr], bv[nc], acc[mr][nc], 0, 0, 0);
    __syncthreads();
  }

  const int crow = (lane >> 4) * 4;
#pragma unroll
  for (int mr = 0; mr < 4; mr++)
#pragma unroll
    for (int nc = 0; nc < 4; nc++)
#pragma unroll
      for (int j = 0; j < 4; j++)
        C[(size_t)(m0 + wm + mr * 16 + crow + j) * N + n0 + wn + nc * 16 + fr] =
            acc[mr][nc][j];
}

// ================= conv1d + silu + dt ========================================
__global__ __launch_bounds__(256) void conv_dt_kernel(
    const float* __restrict__ zx, const float* __restrict__ conv_w,
    const float* __restrict__ conv_b, const float* __restrict__ dt_bias,
    float* __restrict__ xbc, float* __restrict__ dtbuf) {
  const int row = blockIdx.x;
  const int t = row % LLEN;
  const int tid = threadIdx.x;
  for (int c = tid; c < CONVD; c += 256) {
    float accv = conv_b[c];
#pragma unroll
    for (int k = 0; k < 4; k++) {
      const int tt = t - 3 + k;
      if (tt >= 0)
        accv += zx[(size_t)(row - 3 + k) * DPROJP + DINNER + c] * conv_w[c * 4 + k];
    }
    xbc[(size_t)row * CONVD + c] = accv / (1.f + expf(-accv));
  }
  if (tid < NH) {
    const float v = zx[(size_t)row * DPROJP + (DPROJ - NH) + tid] + dt_bias[tid];
    dtbuf[row * NH + tid] = (v > 20.f) ? v : log1pf(expf(v));
  }
}

// ======== per-chunk inclusive cumsum of dt -> la2 (log2 decay), Pp ===========
__global__ __launch_bounds__(128) void cumsum_kernel(
    const float* __restrict__ dtb, const float* __restrict__ A_log,
    float* __restrict__ la2, float* __restrict__ Pp) {
  const int c = blockIdx.x, h = blockIdx.y, b = blockIdx.z;
  const int tid = threadIdx.x, lane = tid & 63;
  const int row = b * LLEN + c * QCH + tid;
  __shared__ float s0;
  float v = dtb[(size_t)row * NH + h];
#pragma unroll
  for (int off = 1; off < 64; off <<= 1) {
    const float u = __shfl_up(v, off, 64);
    if (lane >= off) v += u;
  }
  if (tid == 63) s0 = v;
  __syncthreads();
  if (tid >= 64) v += s0;
  const float la2v = -expf(A_log[h]) * v * 1.44269504088896f;
  la2[(size_t)row * NH + h] = la2v;
  if (tid == 127) Pp[(b * NH + h) * NCH + c] = exp2f(la2v);
}

// ======== prep B/C per (b,chunk): Bbf[t][n], BTbf[n][t], Cbf[t][n] bf16 ======
__global__ __launch_bounds__(256) void prep_bc_kernel(
    const float* __restrict__ xbc, ushort_t* __restrict__ Bbf,
    ushort_t* __restrict__ BTbf, ushort_t* __restrict__ Cbf) {
  const int bc = blockIdx.x;
  const int b = bc / NCH, c = bc % NCH;
  const int row0 = b * LLEN + c * QCH;
  const int tid = threadIdx.x;
  __shared__ ushort_t lb[128][136];
  for (int idx = tid; idx < 128 * 32; idx += 256) {
    const int t = idx >> 5, f4 = (idx & 31) * 4;
    const float4 v = *(const float4*)&xbc[(size_t)(row0 + t) * CONVD + DINNER + f4];
    short4v o;
    o[0] = (short)f2bf(v.x); o[1] = (short)f2bf(v.y);
    o[2] = (short)f2bf(v.z); o[3] = (short)f2bf(v.w);
    *(short4v*)&Bbf[(size_t)(bc * 128 + t) * 128 + f4] = o;
    *(short4v*)&lb[t][f4] = o;
  }
  for (int idx = tid; idx < 128 * 32; idx += 256) {
    const int t = idx >> 5, f4 = (idx & 31) * 4;
    const float4 v = *(const float4*)&xbc[(size_t)(row0 + t) * CONVD + DINNER + DSTATE + f4];
    short4v o;
    o[0] = (short)f2bf(v.x); o[1] = (short)f2bf(v.y);
    o[2] = (short)f2bf(v.z); o[3] = (short)f2bf(v.w);
    *(short4v*)&Cbf[(size_t)(bc * 128 + t) * 128 + f4] = o;
  }
  __syncthreads();
  for (int idx = tid; idx < 128 * 16; idx += 256) {
    const int n = idx & 127, t0 = (idx >> 7) * 8;
    short8v o;
#pragma unroll
    for (int j = 0; j < 8; j++) o[j] = lb[t0 + j][n];
    *(short8v*)&BTbf[(size_t)(bc * 128 + n) * 128 + t0] = o;
  }
}

// ======== prep X'^T per (b,c,h): XpT[p][t] = bf16(x*dt) ======================
__global__ __launch_bounds__(256) void prep_x_kernel(
    const float* __restrict__ xbc, const float* __restrict__ dtb,
    ushort_t* __restrict__ XpT) {
  const int c = blockIdx.x, h = blockIdx.y, b = blockIdx.z;
  const int row0 = b * LLEN + c * QCH;
  const int tid = threadIdx.x;
  __shared__ ushort_t xl[128][56];
  __shared__ float dts[128];
  if (tid < 128) dts[tid] = dtb[(size_t)(row0 + tid) * NH + h];
  __syncthreads();
  for (int idx = tid; idx < 128 * 12; idx += 256) {
    const int r = idx / 12, f4 = (idx % 12) * 4;
    const float4 v = *(const float4*)&xbc[(size_t)(row0 + r) * CONVD + h * HD + f4];
    const float d = dts[r];
    short4v o;
    o[0] = (short)f2bf(v.x * d); o[1] = (short)f2bf(v.y * d);
    o[2] = (short)f2bf(v.z * d); o[3] = (short)f2bf(v.w * d);
    *(short4v*)&xl[r][f4] = o;
  }
  __syncthreads();
  const size_t base = ((size_t)(b * NCH + c) * NH + h) * HD * 128;
  for (int idx = tid; idx < 48 * 16; idx += 256) {
    const int p = idx % 48, t0 = (idx / 48) * 8;
    short8v o;
#pragma unroll
    for (int j = 0; j < 8; j++) o[j] = xl[t0 + j][p];
    *(short8v*)&XpT[base + (size_t)p * 128 + t0] = o;
  }
}

// ======== CBt[b,c][t][s] = C @ B^T (per (b,c), shared across heads) ==========
__global__ __launch_bounds__(256) void cbt_kernel(
    const ushort_t* __restrict__ Cbf, const ushort_t* __restrict__ Bbf,
    float* __restrict__ CBt) {
  const int bc = blockIdx.x;
  const int tid = threadIdx.x, lane = tid & 63, w = tid >> 6;
  const int wm = w * 32;
  const int fr = lane & 15, kk = (lane >> 4) * 8;
  floatx4 acc[2][8];
#pragma unroll
  for (int i = 0; i < 2; i++)
#pragma unroll
    for (int j = 0; j < 8; j++) acc[i][j] = (floatx4){0.f, 0.f, 0.f, 0.f};
  for (int ki = 0; ki < 4; ki++) {
    const int kg = ki * 32 + kk;
    short8v a[2], bv[8];
#pragma unroll
    for (int mt = 0; mt < 2; mt++)
      a[mt] = *(const short8v*)&Cbf[(size_t)(bc * 128 + wm + mt * 16 + fr) * 128 + kg];
#pragma unroll
    for (int nt = 0; nt < 8; nt++)
      bv[nt] = *(const short8v*)&Bbf[(size_t)(bc * 128 + nt * 16 + fr) * 128 + kg];
#pragma unroll
    for (int mt = 0; mt < 2; mt++)
#pragma unroll
      for (int nt = 0; nt < 8; nt++)
        acc[mt][nt] = __builtin_amdgcn_mfma_f32_16x16x32_bf16(
            a[mt], bv[nt], acc[mt][nt], 0, 0, 0);
  }
  const int crow = (lane >> 4) * 4;
#pragma unroll
  for (int mt = 0; mt < 2; mt++)
#pragma unroll
    for (int nt = 0; nt < 8; nt++)
#pragma unroll
      for (int j = 0; j < 4; j++)
        CBt[(size_t)(bc * 128 + wm + mt * 16 + crow + j) * 128 + nt * 16 + fr] =
            acc[mt][nt][j];
}

// ======== Pass A: S^T[p][n] = sum_t w_t X'[t,p] B[t,n]  (MFMA) ===============
__global__ __launch_bounds__(256) void stateA_kernel(
    const ushort_t* __restrict__ XpT, const ushort_t* __restrict__ BTbf,
    const float* __restrict__ la2, float* __restrict__ Sc) {
  const int c = blockIdx.x, h = blockIdx.y, b = blockIdx.z;
  const int bc = b * NCH + c, bh = b * NH + h;
  const int row0 = b * LLEN + c * QCH;
  const int tid = threadIdx.x, lane = tid & 63, w = tid >> 6;
  __shared__ float ew[128];
  const float laL = la2[(size_t)(row0 + 127) * NH + h];
  if (tid < 128) ew[tid] = exp2f(laL - la2[(size_t)(row0 + tid) * NH + h]);
  __syncthreads();
  const int wn = w * 32;
  const int fr = lane & 15, kk = (lane >> 4) * 8;
  const size_t xbase = ((size_t)bc * NH + h) * HD * 128;
  floatx4 acc[3][2];
#pragma unroll
  for (int i = 0; i < 3; i++)
#pragma unroll
    for (int j = 0; j < 2; j++) acc[i][j] = (floatx4){0.f, 0.f, 0.f, 0.f};
  for (int ki = 0; ki < 4; ki++) {
    const int kg = ki * 32 + kk;
    short8v a[3], bv[2];
#pragma unroll
    for (int mt = 0; mt < 3; mt++) {
      const short8v raw = *(const short8v*)&XpT[xbase + (size_t)(mt * 16 + fr) * 128 + kg];
      short8v s;
#pragma unroll
      for (int e = 0; e < 8; e++) s[e] = (short)f2bf(bf2f(raw[e]) * ew[kg + e]);
      a[mt] = s;
    }
#pragma unroll
    for (int nt = 0; nt < 2; nt++)
      bv[nt] = *(const short8v*)&BTbf[(size_t)(bc * 128 + wn + nt * 16 + fr) * 128 + kg];
#pragma unroll
    for (int mt = 0; mt < 3; mt++)
#pragma unroll
      for (int nt = 0; nt < 2; nt++)
        acc[mt][nt] = __builtin_amdgcn_mfma_f32_16x16x32_bf16(
            a[mt], bv[nt], acc[mt][nt], 0, 0, 0);
  }
  const int crow = (lane >> 4) * 4;
  float* sc = Sc + (size_t)(bh * NCH + c) * (HD * DSTATE);
#pragma unroll
  for (int mt = 0; mt < 3; mt++)
#pragma unroll
    for (int nt = 0; nt < 2; nt++)
#pragma unroll
      for (int j = 0; j < 4; j++)
        sc[(size_t)(mt * 16 + crow + j) * 128 + wn + nt * 16 + fr] = acc[mt][nt][j];
}

// ===== Pass B: sequential combine across 8 chunks (in-place: Sc -> Hc) =======
__global__ __launch_bounds__(256) void chunk_combine_kernel(
    float* __restrict__ Sc, const float* __restrict__ Pp) {
  const int bh = blockIdx.x;
  const int tid = threadIdx.x;
  for (int e = tid; e < HD * DSTATE; e += 256) {
    float hv = 0.f;
#pragma unroll
    for (int c = 0; c < NCH; c++) {
      const size_t idx = ((size_t)(bh * NCH + c)) * HD * DSTATE + e;
      const float sv = Sc[idx];
      Sc[idx] = hv;
      hv = hv * Pp[bh * NCH + c] + sv;
    }
  }
}

// ======== Pass C: Y = (CBt .* mask) @ X' + (C .* exp2(la)) @ h_in ============
__global__ __launch_bounds__(256) void ykernel(
    const float* __restrict__ CBt, const ushort_t* __restrict__ XpT,
    const ushort_t* __restrict__ Cbf, const float* __restrict__ Hc,
    const float* __restrict__ la2, float* __restrict__ y) {
  const int c = blockIdx.x, h = blockIdx.y, b = blockIdx.z;
  const int bc = b * NCH + c, bh = b * NH + h;
  const int row0 = b * LLEN + c * QCH;
  const int tid = threadIdx.x, lane = tid & 63, w = tid >> 6;
  __shared__ float laL[128], el[128];
  if (tid < 128) {
    const float v = la2[(size_t)(row0 + tid) * NH + h];
    laL[tid] = v; el[tid] = exp2f(v);
  }
  __syncthreads();
  const int wm = w * 32;
  const int fr = lane & 15, kk = (lane >> 4) * 8;
  const size_t xbase = ((size_t)bc * NH + h) * HD * 128;
  const float* hin = Hc + (size_t)(bh * NCH + c) * (HD * DSTATE);
  floatx4 acc[2][3];
#pragma unroll
  for (int i = 0; i < 2; i++)
#pragma unroll
    for (int j = 0; j < 3; j++) acc[i][j] = (floatx4){0.f, 0.f, 0.f, 0.f};

  // part 1: intra-chunk masked P @ X'
  for (int ki = 0; ki < 4; ki++) {
    const int kg = ki * 32 + kk;
    short8v a[2], bv[3];
#pragma unroll
    for (int mt = 0; mt < 2; mt++) {
      const int t = wm + mt * 16 + fr;
      const float lt = laL[t];
      const float* cb = &CBt[(size_t)(bc * 128 + t) * 128 + kg];
      const float4 u0 = *(const float4*)cb;
      const float4 u1 = *(const float4*)(cb + 4);
      const float f[8] = {u0.x, u0.y, u0.z, u0.w, u1.x, u1.y, u1.z, u1.w};
      short8v s;
#pragma unroll
      for (int e = 0; e < 8; e++) {
        const int sidx = kg + e;
        const float m = (t >= sidx) ? exp2f(lt - laL[sidx]) : 0.f;
        s[e] = (short)f2bf(f[e] * m);
      }
      a[mt] = s;
    }
#pragma unroll
    for (int nt = 0; nt < 3; nt++)
      bv[nt] = *(const short8v*)&XpT[xbase + (size_t)(nt * 16 + fr) * 128 + kg];
#pragma unroll
    for (int mt = 0; mt < 2; mt++)
#pragma unroll
      for (int nt = 0; nt < 3; nt++)
        acc[mt][nt] = __builtin_amdgcn_mfma_f32_16x16x32_bf16(
            a[mt], bv[nt], acc[mt][nt], 0, 0, 0);
  }
  // part 2: inter-chunk (C .* el) @ h_in
  for (int ki = 0; ki < 4; ki++) {
    const int kg = ki * 32 + kk;
    short8v a[2], bv[3];
#pragma unroll
    for (int mt = 0; mt < 2; mt++) {
      const int t = wm + mt * 16 + fr;
      const float scl = el[t];
      const short8v raw = *(const short8v*)&Cbf[(size_t)(bc * 128 + t) * 128 + kg];
      short8v s;
#pragma unroll
      for (int e = 0; e < 8; e++) s[e] = (short)f2bf(bf2f(raw[e]) * scl);
      a[mt] = s;
    }
#pragma unroll
    for (int nt = 0; nt < 3; nt++) {
      const float* hp = &hin[(size_t)(nt * 16 + fr) * 128 + kg];
      const float4 u0 = *(const float4*)hp;
      const float4 u1 = *(const float4*)(hp + 4);
      const float f[8] = {u0.x, u0.y, u0.z, u0.w, u1.x, u1.y, u1.z, u1.w};
      short8v s;
#pragma unroll
      for (int e = 0; e < 8; e++) s[e] = (short)f2bf(f[e]);
      bv[nt] = s;
    }
#pragma unroll
    for (int mt = 0; mt < 2; mt++)
#pragma unroll
      for (int nt = 0; nt < 3; nt++)
        acc[mt][nt] = __builtin_amdgcn_mfma_f32_16x16x32_bf16(
            a[mt], bv[nt], acc[mt][nt], 0, 0, 0);
  }
  const int crow = (lane >> 4) * 4;
#pragma unroll
  for (int mt = 0; mt < 2; mt++)
#pragma unroll
    for (int nt = 0; nt < 3; nt++)
#pragma unroll
      for (int j = 0; j < 4; j++) {
        const int row = row0 + wm + mt * 16 + crow + j;
        y[(size_t)row * DINNER + h * HD + nt * 16 + fr] = acc[mt][nt][j];
      }
}

// ===== gate (silu(z)) + RMSNorm over 1536, emit bf16 for out_proj GEMM =======
__global__ __launch_bounds__(256) void gate_rms_kernel(
    const float* __restrict__ zx, const float* __restrict__ xbc,
    const float* __restrict__ Dv, const float* __restrict__ rms_w,
    const float* __restrict__ y, ushort_t* __restrict__ ybf) {
  const int row = blockIdx.x;
  const int tid = threadIdx.x;
  __shared__ float sred[4];
  float g[6];
  float ss = 0.f;
#pragma unroll
  for (int i = 0; i < 6; i++) {
    const int e = tid + i * 256;
    const float yv = y[(size_t)row * DINNER + e] + Dv[e / HD] * xbc[(size_t)row * CONVD + e];
    const float z = zx[(size_t)row * DPROJP + e];
    const float gv = yv * (z / (1.f + expf(-z)));
    g[i] = gv;
    ss += gv * gv;
  }
#pragma unroll
  for (int off = 32; off; off >>= 1) ss += __shfl_down(ss, off, 64);
  if ((tid & 63) == 0) sred[tid >> 6] = ss;
  __syncthreads();
  const float tot = sred[0] + sred[1] + sred[2] + sred[3];
  const float scale = rsqrtf(tot / DINNER + 1e-5f);
#pragma unroll
  for (int i = 0; i < 6; i++) {
    const int e = tid + i * 256;
    ybf[(size_t)row * DINNER + e] = f2bf(g[i] * scale * rms_w[e]);
  }
}

// ================= residual + LayerNorm over 768 =============================
__global__ __launch_bounds__(256) void resid_ln_kernel(
    const float* __restrict__ go, const float* __restrict__ x,
    const float* __restrict__ ln_w, const float* __restrict__ ln_b,
    float* __restrict__ out) {
  const int row = blockIdx.x;
  const int tid = threadIdx.x;
  __shared__ float sred[4];
  __shared__ float sred2[4];
  float r[3];
  float s = 0.f;
#pragma unroll
  for (int i = 0; i < 3; i++) {
    const int e = tid + i * 256;
    r[i] = go[(size_t)row * DMODEL + e] + x[(size_t)row * DMODEL + e];
    s += r[i];
  }
#pragma unroll
  for (int off = 32; off; off >>= 1) s += __shfl_down(s, off, 64);
  if ((tid & 63) == 0) sred[tid >> 6] = s;
  __syncthreads();
  const float mu = (sred[0] + sred[1] + sred[2] + sred[3]) * (1.f / DMODEL);
  float s2 = 0.f;
#pragma unroll
  for (int i = 0; i < 3; i++) {
    const float d = r[i] - mu;
    s2 += d * d;
  }
#pragma unroll
  for (int off = 32; off; off >>= 1) s2 += __shfl_down(s2, off, 64);
  if ((tid & 63) == 0) sred2[tid >> 6] = s2;
  __syncthreads();
  const float var = (sred2[0] + sred2[1] + sred2[2] + sred2[3]) * (1.f / DMODEL);
  const float inv = rsqrtf(var + 1e-5f);
#pragma unroll
  for (int i = 0; i < 3; i++) {
    const int e = tid + i * 256;
    out[(size_t)row * DMODEL + e] = (r[i] - mu) * inv * ln_w[e] + ln_b[e];
  }
}

// ================= launch ====================================================
extern "C" void kernel_launch(void* const* d_in, const int* in_sizes, int n_in,
                              void* d_out, int out_size, void* d_ws, size_t ws_size,
                              hipStream_t stream) {
  const float* x          = (const float*)d_in[0];
  const float* in_proj_w  = (const float*)d_in[1];
  const float* conv_w     = (const float*)d_in[2];
  const float* conv_b     = (const float*)d_in[3];
  const float* dt_bias    = (const float*)d_in[4];
  const float* A_log      = (const float*)d_in[5];
  const float* Dv         = (const float*)d_in[6];
  const float* rms_w      = (const float*)d_in[7];
  const float* out_proj_w = (const float*)d_in[8];
  const float* ln_w       = (const float*)d_in[9];
  const float* ln_b       = (const float*)d_in[10];
  float* out = (float*)d_out;
  float* ws  = (float*)d_ws;

  float* zx   = ws + OFF_ZX;
  float* xbc  = ws + OFF_XBC;
  float* dtb  = ws + OFF_DT;
  float* la2  = ws + OFF_LA;
  float* Sc   = ws + OFF_SC;          // Hc after in-place combine
  float* ybuf = ws + OFF_Y;
  float* Pp   = ws + OFF_PP;
  float* CBt  = ws + OFF_CBT;
  ushort_t* Cbf  = (ushort_t*)(ws + OFF_CBF);
  ushort_t* Bbf  = (ushort_t*)(ws + OFF_BBF);
  ushort_t* BTbf = (ushort_t*)(ws + OFF_BTBF);
  ushort_t* XpT  = (ushort_t*)(ws + OFF_XPT);

  // aliased staging buffers
  ushort_t* xbf   = (ushort_t*)(ws + OFF_Y);                 // GEMM1 phase (ybuf dead)
  ushort_t* ipwbf = (ushort_t*)(ws + OFF_Y + 786432);
  ushort_t* ybf   = (ushort_t*)(ws + OFF_SC);                // GEMM2 phase (Sc dead)
  ushort_t* opwbf = (ushort_t*)(ws + OFF_SC + 1572864);
  float*    go    = ws + OFF_ZX;                             // GEMM2 out (zx dead)

  // 0) convert inputs to bf16
  convert_bf16_kernel<<<(ROWS * DMODEL / 8 + 255) / 256, 256, 0, stream>>>(
      x, xbf, ROWS * DMODEL / 8);
  convert_wpad_kernel<<<(DPROJP * DMODEL / 8 + 255) / 256, 256, 0, stream>>>(
      in_proj_w, ipwbf);

  // 1) in_proj
  gemm_bf16<<<dim3(DPROJP / 128, ROWS / 128), 256, 0, stream>>>(
      xbf, ipwbf, zx, ROWS, DPROJP, DMODEL);

  // 2) conv + silu + dt
  conv_dt_kernel<<<ROWS, 256, 0, stream>>>(zx, conv_w, conv_b, dt_bias, xbc, dtb);

  // 3) chunked scan, matrix form
  cumsum_kernel<<<dim3(NCH, NH, BDIM), 128, 0, stream>>>(dtb, A_log, la2, Pp);
  prep_bc_kernel<<<BDIM * NCH, 256, 0, stream>>>(xbc, Bbf, BTbf, Cbf);
  prep_x_kernel<<<dim3(NCH, NH, BDIM), 256, 0, stream>>>(xbc, dtb, XpT);
  cbt_kernel<<<BDIM * NCH, 256, 0, stream>>>(Cbf, Bbf, CBt);
  stateA_kernel<<<dim3(NCH, NH, BDIM), 256, 0, stream>>>(XpT, BTbf, la2, Sc);
  chunk_combine_kernel<<<BDIM * NH, 256, 0, stream>>>(Sc, Pp);
  ykernel<<<dim3(NCH, NH, BDIM), 256, 0, stream>>>(CBt, XpT, Cbf, Sc, la2, ybuf);

  // 4) gate + RMSNorm -> bf16
  gate_rms_kernel<<<ROWS, 256, 0, stream>>>(zx, xbc, Dv, rms_w, ybuf, ybf);

  // 5) out_proj
  convert_bf16_kernel<<<(DMODEL * DINNER / 8 + 255) / 256, 256, 0, stream>>>(
      out_proj_w, opwbf, DMODEL * DINNER / 8);
  gemm_bf16<<<dim3(DMODEL / 128, ROWS / 128), 256, 0, stream>>>(
      ybf, opwbf, go, ROWS, DMODEL, DINNER);

  // 6) residual + LayerNorm
  resid_ln_kernel<<<ROWS, 256, 0, stream>>>(go, x, ln_w, ln_b, out);
}

// Round 8
// 234.411 us; speedup vs baseline: 3.0304x; 1.0928x over previous
//
#include <hip/hip_runtime.h>
#include <math.h>

#define BDIM 2
#define LLEN 1024
#define DMODEL 768
#define DINNER 1536
#define DSTATE 128
#define NH 32
#define HD 48
#define CONVD 1792
#define DPROJ 3360
#define DPROJP 3456
#define QCH 128
#define NCH 8
#define ROWS (BDIM*LLEN)

typedef unsigned short ushort_t;
typedef __attribute__((ext_vector_type(4))) short short4v;
typedef __attribute__((ext_vector_type(8))) short short8v;
typedef __attribute__((ext_vector_type(4))) float floatx4;

// ---- workspace layout (float units) ----
// zx_bf  u16 [2048][3456]   @0          (3,538,944 f)   ; go f32 aliases after gate_rms
// xbc_bf u16 [2048][1792]   @3,538,944  (1,835,008 f)
// dtb    f32 [2048][32]     @5,373,952  (65,536 f)
// la2    f32 [2048][32]     @5,439,488  (65,536 f)
// Sc     f32 [64][8][48][128] @5,505,024 (3,145,728 f)  ; ybf+opwbf alias in GEMM2 phase
// ybuf   f32 [2048][1536]   @8,650,752  (3,145,728 f)   ; xbf+ipwbf alias in GEMM1 phase
// Pp     f32 [512]          @11,796,480 (1,024 f)
// CBt    f32 [16][128][128] @11,797,504 (262,144 f)
// BTbf   u16 [16][128][128] @12,059,648 (131,072 f)
// XpT    u16 [16][32][48][128] @12,190,720 (1,572,864 f)
// total 13,763,584 floats (~52.5 MB)
#define OFF_ZX   0ull
#define OFF_XBC  3538944ull
#define OFF_DT   5373952ull
#define OFF_LA   5439488ull
#define OFF_SC   5505024ull
#define OFF_Y    8650752ull
#define OFF_PP   11796480ull
#define OFF_CBT  11797504ull
#define OFF_BTBF 12059648ull
#define OFF_XPT  12190720ull

__device__ __forceinline__ ushort_t f2bf(float f) {
  union { float f; unsigned int u; } v; v.f = f;
  return (ushort_t)((v.u + 0x7FFFu + ((v.u >> 16) & 1u)) >> 16);
}
__device__ __forceinline__ float bf2f(short s) {
  union { unsigned int u; float f; } v; v.u = ((unsigned int)(ushort_t)s) << 16;
  return v.f;
}

#define GLOAD_LDS16(gptr, lptr) \
  __builtin_amdgcn_global_load_lds( \
      (const __attribute__((address_space(1))) void*)(gptr), \
      (__attribute__((address_space(3))) void*)(lptr), 16, 0, 0)

// ===== fused input converts: blocks [0,768) x->xbf ; [768,2064) ipw->ipwbf ===
__global__ __launch_bounds__(256) void convert_in_kernel(
    const float* __restrict__ x, const float* __restrict__ w,
    ushort_t* __restrict__ xbf, ushort_t* __restrict__ ipwbf) {
  const int blk = blockIdx.x;
  if (blk < 768) {
    const int i = blk * 256 + threadIdx.x;        // over 196,608
    const float4 a = ((const float4*)x)[i * 2];
    const float4 b = ((const float4*)x)[i * 2 + 1];
    short8v o;
    o[0] = (short)f2bf(a.x); o[1] = (short)f2bf(a.y);
    o[2] = (short)f2bf(a.z); o[3] = (short)f2bf(a.w);
    o[4] = (short)f2bf(b.x); o[5] = (short)f2bf(b.y);
    o[6] = (short)f2bf(b.z); o[7] = (short)f2bf(b.w);
    *(short8v*)(xbf + (size_t)i * 8) = o;
  } else {
    const int i = (blk - 768) * 256 + threadIdx.x; // over 331,776 = 3456*96
    const int row = i / (DMODEL / 8);
    short8v o;
    if (row < DPROJ) {
      const float4 a = ((const float4*)w)[i * 2];
      const float4 b = ((const float4*)w)[i * 2 + 1];
      o[0] = (short)f2bf(a.x); o[1] = (short)f2bf(a.y);
      o[2] = (short)f2bf(a.z); o[3] = (short)f2bf(a.w);
      o[4] = (short)f2bf(b.x); o[5] = (short)f2bf(b.y);
      o[6] = (short)f2bf(b.z); o[7] = (short)f2bf(b.w);
    } else {
      for (int j = 0; j < 8; j++) o[j] = 0;
    }
    *(short8v*)(ipwbf + (size_t)i * 8) = o;
  }
}

// ================= opw f32 -> bf16 (must run after scan frees Sc) ============
__global__ __launch_bounds__(256) void convert_bf16_kernel(
    const float* __restrict__ in, ushort_t* __restrict__ out, int n8) {
  const int i = blockIdx.x * 256 + threadIdx.x;
  if (i >= n8) return;
  const float4 a = ((const float4*)in)[i * 2];
  const float4 b = ((const float4*)in)[i * 2 + 1];
  short8v o;
  o[0] = (short)f2bf(a.x); o[1] = (short)f2bf(a.y);
  o[2] = (short)f2bf(a.z); o[3] = (short)f2bf(a.w);
  o[4] = (short)f2bf(b.x); o[5] = (short)f2bf(b.y);
  o[6] = (short)f2bf(b.z); o[7] = (short)f2bf(b.w);
  *(short8v*)(out + (size_t)i * 8) = o;
}

// ============ bf16 MFMA GEMM, bf16 output (in_proj) ==========================
__global__ __launch_bounds__(256) void gemm_bf16_bfout(
    const ushort_t* __restrict__ A, const ushort_t* __restrict__ B,
    ushort_t* __restrict__ C, int M, int N, int K) {
  __shared__ __align__(16) ushort_t As[128 * 32];
  __shared__ __align__(16) ushort_t Bs[128 * 32];
  const int tid = threadIdx.x, lane = tid & 63, w = tid >> 6;
  const int wm = (w >> 1) * 64, wn = (w & 1) * 64;
  const int m0 = blockIdx.y * 128, n0 = blockIdx.x * 128;
  floatx4 acc[4][4];
#pragma unroll
  for (int i = 0; i < 4; i++)
#pragma unroll
    for (int j = 0; j < 4; j++) acc[i][j] = (floatx4){0.f, 0.f, 0.f, 0.f};
  const int srow = tid >> 2, skc = (tid & 3) * 8;
  const int kk = (lane >> 4) * 8, fr = lane & 15;
  for (int k0 = 0; k0 < K; k0 += 32) {
#pragma unroll
    for (int i = 0; i < 2; i++) {
      GLOAD_LDS16(A + (size_t)(m0 + i * 64 + srow) * K + k0 + skc,
                  As + (i * 64 + srow) * 32 + skc);
      GLOAD_LDS16(B + (size_t)(n0 + i * 64 + srow) * K + k0 + skc,
                  Bs + (i * 64 + srow) * 32 + skc);
    }
    __syncthreads();
    short8v a[4], bv[4];
#pragma unroll
    for (int mr = 0; mr < 4; mr++)
      a[mr] = *(const short8v*)(As + (wm + mr * 16 + fr) * 32 + kk);
#pragma unroll
    for (int nc = 0; nc < 4; nc++)
      bv[nc] = *(const short8v*)(Bs + (wn + nc * 16 + fr) * 32 + kk);
#pragma unroll
    for (int mr = 0; mr < 4; mr++)
#pragma unroll
      for (int nc = 0; nc < 4; nc++)
        acc[mr][nc] = __builtin_amdgcn_mfma_f32_16x16x32_bf16(
            a[mr], bv[nc], acc[mr][nc], 0, 0, 0);
    __syncthreads();
  }
  const int crow = (lane >> 4) * 4;
#pragma unroll
  for (int mr = 0; mr < 4; mr++)
#pragma unroll
    for (int nc = 0; nc < 4; nc++)
#pragma unroll
      for (int j = 0; j < 4; j++)
        C[(size_t)(m0 + wm + mr * 16 + crow + j) * N + n0 + wn + nc * 16 + fr] =
            f2bf(acc[mr][nc][j]);
}

// ============ bf16 MFMA GEMM, BN=64, fp32 out (out_proj; 192 blocks) =========
__global__ __launch_bounds__(256) void gemm_bf16_n64(
    const ushort_t* __restrict__ A, const ushort_t* __restrict__ B,
    float* __restrict__ C, int M, int N, int K) {
  __shared__ __align__(16) ushort_t As[128 * 32];
  __shared__ __align__(16) ushort_t Bs[64 * 32];
  const int tid = threadIdx.x, lane = tid & 63, w = tid >> 6;
  const int wm = (w >> 1) * 64, wn = (w & 1) * 32;
  const int m0 = blockIdx.y * 128, n0 = blockIdx.x * 64;
  floatx4 acc[4][2];
#pragma unroll
  for (int i = 0; i < 4; i++)
#pragma unroll
    for (int j = 0; j < 2; j++) acc[i][j] = (floatx4){0.f, 0.f, 0.f, 0.f};
  const int srow = tid >> 2, skc = (tid & 3) * 8;
  const int kk = (lane >> 4) * 8, fr = lane & 15;
  for (int k0 = 0; k0 < K; k0 += 32) {
#pragma unroll
    for (int i = 0; i < 2; i++)
      GLOAD_LDS16(A + (size_t)(m0 + i * 64 + srow) * K + k0 + skc,
                  As + (i * 64 + srow) * 32 + skc);
    GLOAD_LDS16(B + (size_t)(n0 + srow) * K + k0 + skc, Bs + srow * 32 + skc);
    __syncthreads();
    short8v a[4], bv[2];
#pragma unroll
    for (int mr = 0; mr < 4; mr++)
      a[mr] = *(const short8v*)(As + (wm + mr * 16 + fr) * 32 + kk);
#pragma unroll
    for (int nc = 0; nc < 2; nc++)
      bv[nc] = *(const short8v*)(Bs + (wn + nc * 16 + fr) * 32 + kk);
#pragma unroll
    for (int mr = 0; mr < 4; mr++)
#pragma unroll
      for (int nc = 0; nc < 2; nc++)
        acc[mr][nc] = __builtin_amdgcn_mfma_f32_16x16x32_bf16(
            a[mr], bv[nc], acc[mr][nc], 0, 0, 0);
    __syncthreads();
  }
  const int crow = (lane >> 4) * 4;
#pragma unroll
  for (int mr = 0; mr < 4; mr++)
#pragma unroll
    for (int nc = 0; nc < 2; nc++)
#pragma unroll
      for (int j = 0; j < 4; j++)
        C[(size_t)(m0 + wm + mr * 16 + crow + j) * N + n0 + wn + nc * 16 + fr] =
            acc[mr][nc][j];
}

// ================= conv1d + silu + dt (bf16 in / bf16 out) ===================
__global__ __launch_bounds__(256) void conv_dt_kernel(
    const ushort_t* __restrict__ zxb, const float* __restrict__ conv_w,
    const float* __restrict__ conv_b, const float* __restrict__ dt_bias,
    ushort_t* __restrict__ xbcb, float* __restrict__ dtbuf) {
  const int row = blockIdx.x;
  const int t = row % LLEN;
  const int tid = threadIdx.x;
  for (int g = tid; g < CONVD / 4; g += 256) {   // 448 groups of 4 channels
    const int c = g * 4;
    const float4 cb = *(const float4*)&conv_b[c];
    float acc0 = cb.x, acc1 = cb.y, acc2 = cb.z, acc3 = cb.w;
    float4 cw[4];
#pragma unroll
    for (int j = 0; j < 4; j++) cw[j] = *(const float4*)&conv_w[(c + j) * 4];
#pragma unroll
    for (int k = 0; k < 4; k++) {
      if (t - 3 + k >= 0) {
        const short4v v = *(const short4v*)&zxb[(size_t)(row - 3 + k) * DPROJP + DINNER + c];
        acc0 += bf2f(v[0]) * ((const float*)&cw[0])[k];
        acc1 += bf2f(v[1]) * ((const float*)&cw[1])[k];
        acc2 += bf2f(v[2]) * ((const float*)&cw[2])[k];
        acc3 += bf2f(v[3]) * ((const float*)&cw[3])[k];
      }
    }
    short4v o;
    o[0] = (short)f2bf(acc0 / (1.f + expf(-acc0)));
    o[1] = (short)f2bf(acc1 / (1.f + expf(-acc1)));
    o[2] = (short)f2bf(acc2 / (1.f + expf(-acc2)));
    o[3] = (short)f2bf(acc3 / (1.f + expf(-acc3)));
    *(short4v*)&xbcb[(size_t)row * CONVD + c] = o;
  }
  if (tid < NH) {
    const float v = bf2f(zxb[(size_t)row * DPROJP + (DPROJ - NH) + tid]) + dt_bias[tid];
    dtbuf[row * NH + tid] = (v > 20.f) ? v : log1pf(expf(v));
  }
}

// ======== per-chunk inclusive cumsum of dt -> la2 (log2 decay), Pp ===========
__global__ __launch_bounds__(128) void cumsum_kernel(
    const float* __restrict__ dtb, const float* __restrict__ A_log,
    float* __restrict__ la2, float* __restrict__ Pp) {
  const int c = blockIdx.x, h = blockIdx.y, b = blockIdx.z;
  const int tid = threadIdx.x, lane = tid & 63;
  const int row = b * LLEN + c * QCH + tid;
  __shared__ float s0;
  float v = dtb[(size_t)row * NH + h];
#pragma unroll
  for (int off = 1; off < 64; off <<= 1) {
    const float u = __shfl_up(v, off, 64);
    if (lane >= off) v += u;
  }
  if (tid == 63) s0 = v;
  __syncthreads();
  if (tid >= 64) v += s0;
  const float la2v = -expf(A_log[h]) * v * 1.44269504088896f;
  la2[(size_t)row * NH + h] = la2v;
  if (tid == 127) Pp[(b * NH + h) * NCH + c] = exp2f(la2v);
}

// ======== prep: BTbf[n][t] transpose of B (per b,chunk) ======================
__global__ __launch_bounds__(256) void prep_bt_kernel(
    const ushort_t* __restrict__ xbcb, ushort_t* __restrict__ BTbf) {
  const int bc = blockIdx.x;
  const int b = bc / NCH, c = bc % NCH;
  const int row0 = b * LLEN + c * QCH;
  const int tid = threadIdx.x;
  __shared__ ushort_t lb[128][136];
  for (int idx = tid; idx < 128 * 32; idx += 256) {
    const int t = idx >> 5, f4 = (idx & 31) * 4;
    const short4v v = *(const short4v*)&xbcb[(size_t)(row0 + t) * CONVD + DINNER + f4];
    *(short4v*)&lb[t][f4] = v;
  }
  __syncthreads();
  for (int idx = tid; idx < 128 * 16; idx += 256) {
    const int n = idx & 127, t0 = (idx >> 7) * 8;
    short8v o;
#pragma unroll
    for (int j = 0; j < 8; j++) o[j] = lb[t0 + j][n];
    *(short8v*)&BTbf[(size_t)(bc * 128 + n) * 128 + t0] = o;
  }
}

// ======== prep X'^T per (b,c,h): XpT[p][t] = bf16(x*dt) ======================
__global__ __launch_bounds__(256) void prep_x_kernel(
    const ushort_t* __restrict__ xbcb, const float* __restrict__ dtb,
    ushort_t* __restrict__ XpT) {
  const int c = blockIdx.x, h = blockIdx.y, b = blockIdx.z;
  const int row0 = b * LLEN + c * QCH;
  const int tid = threadIdx.x;
  __shared__ ushort_t xl[128][56];
  __shared__ float dts[128];
  if (tid < 128) dts[tid] = dtb[(size_t)(row0 + tid) * NH + h];
  __syncthreads();
  for (int idx = tid; idx < 128 * 12; idx += 256) {
    const int r = idx / 12, f4 = (idx % 12) * 4;
    const short4v v = *(const short4v*)&xbcb[(size_t)(row0 + r) * CONVD + h * HD + f4];
    const float d = dts[r];
    short4v o;
    o[0] = (short)f2bf(bf2f(v[0]) * d); o[1] = (short)f2bf(bf2f(v[1]) * d);
    o[2] = (short)f2bf(bf2f(v[2]) * d); o[3] = (short)f2bf(bf2f(v[3]) * d);
    *(short4v*)&xl[r][f4] = o;
  }
  __syncthreads();
  const size_t base = ((size_t)(b * NCH + c) * NH + h) * HD * 128;
  for (int idx = tid; idx < 48 * 16; idx += 256) {
    const int p = idx % 48, t0 = (idx / 48) * 8;
    short8v o;
#pragma unroll
    for (int j = 0; j < 8; j++) o[j] = xl[t0 + j][p];
    *(short8v*)&XpT[base + (size_t)p * 128 + t0] = o;
  }
}

// ======== CBt[b,c][t][s] = C @ B^T (B,C read directly from xbc_bf) ===========
__global__ __launch_bounds__(256) void cbt_kernel(
    const ushort_t* __restrict__ xbcb, float* __restrict__ CBt) {
  const int bc = blockIdx.x;
  const int b = bc / NCH, c = bc % NCH;
  const int row0 = b * LLEN + c * QCH;
  const int tid = threadIdx.x, lane = tid & 63, w = tid >> 6;
  const int wm = w * 32;
  const int fr = lane & 15, kk = (lane >> 4) * 8;
  floatx4 acc[2][8];
#pragma unroll
  for (int i = 0; i < 2; i++)
#pragma unroll
    for (int j = 0; j < 8; j++) acc[i][j] = (floatx4){0.f, 0.f, 0.f, 0.f};
  for (int ki = 0; ki < 4; ki++) {
    const int kg = ki * 32 + kk;
    short8v a[2], bv[8];
#pragma unroll
    for (int mt = 0; mt < 2; mt++)
      a[mt] = *(const short8v*)&xbcb[(size_t)(row0 + wm + mt * 16 + fr) * CONVD +
                                     DINNER + DSTATE + kg];
#pragma unroll
    for (int nt = 0; nt < 8; nt++)
      bv[nt] = *(const short8v*)&xbcb[(size_t)(row0 + nt * 16 + fr) * CONVD +
                                      DINNER + kg];
#pragma unroll
    for (int mt = 0; mt < 2; mt++)
#pragma unroll
      for (int nt = 0; nt < 8; nt++)
        acc[mt][nt] = __builtin_amdgcn_mfma_f32_16x16x32_bf16(
            a[mt], bv[nt], acc[mt][nt], 0, 0, 0);
  }
  const int crow = (lane >> 4) * 4;
#pragma unroll
  for (int mt = 0; mt < 2; mt++)
#pragma unroll
    for (int nt = 0; nt < 8; nt++)
#pragma unroll
      for (int j = 0; j < 4; j++)
        CBt[(size_t)(bc * 128 + wm + mt * 16 + crow + j) * 128 + nt * 16 + fr] =
            acc[mt][nt][j];
}

// ======== Pass A: S^T[p][n] = sum_t w_t X'[t,p] B[t,n]  (MFMA) ===============
__global__ __launch_bounds__(256) void stateA_kernel(
    const ushort_t* __restrict__ XpT, const ushort_t* __restrict__ BTbf,
    const float* __restrict__ la2, float* __restrict__ Sc) {
  const int c = blockIdx.x, h = blockIdx.y, b = blockIdx.z;
  const int bc = b * NCH + c, bh = b * NH + h;
  const int row0 = b * LLEN + c * QCH;
  const int tid = threadIdx.x, lane = tid & 63, w = tid >> 6;
  __shared__ float ew[128];
  const float laL = la2[(size_t)(row0 + 127) * NH + h];
  if (tid < 128) ew[tid] = exp2f(laL - la2[(size_t)(row0 + tid) * NH + h]);
  __syncthreads();
  const int wn = w * 32;
  const int fr = lane & 15, kk = (lane >> 4) * 8;
  const size_t xbase = ((size_t)bc * NH + h) * HD * 128;
  floatx4 acc[3][2];
#pragma unroll
  for (int i = 0; i < 3; i++)
#pragma unroll
    for (int j = 0; j < 2; j++) acc[i][j] = (floatx4){0.f, 0.f, 0.f, 0.f};
  for (int ki = 0; ki < 4; ki++) {
    const int kg = ki * 32 + kk;
    short8v a[3], bv[2];
#pragma unroll
    for (int mt = 0; mt < 3; mt++) {
      const short8v raw = *(const short8v*)&XpT[xbase + (size_t)(mt * 16 + fr) * 128 + kg];
      short8v s;
#pragma unroll
      for (int e = 0; e < 8; e++) s[e] = (short)f2bf(bf2f(raw[e]) * ew[kg + e]);
      a[mt] = s;
    }
#pragma unroll
    for (int nt = 0; nt < 2; nt++)
      bv[nt] = *(const short8v*)&BTbf[(size_t)(bc * 128 + wn + nt * 16 + fr) * 128 + kg];
#pragma unroll
    for (int mt = 0; mt < 3; mt++)
#pragma unroll
      for (int nt = 0; nt < 2; nt++)
        acc[mt][nt] = __builtin_amdgcn_mfma_f32_16x16x32_bf16(
            a[mt], bv[nt], acc[mt][nt], 0, 0, 0);
  }
  const int crow = (lane >> 4) * 4;
  float* sc = Sc + (size_t)(bh * NCH + c) * (HD * DSTATE);
#pragma unroll
  for (int mt = 0; mt < 3; mt++)
#pragma unroll
    for (int nt = 0; nt < 2; nt++)
#pragma unroll
      for (int j = 0; j < 4; j++)
        sc[(size_t)(mt * 16 + crow + j) * 128 + wn + nt * 16 + fr] = acc[mt][nt][j];
}

// ===== Pass B: sequential combine across 8 chunks (in-place) =================
__global__ __launch_bounds__(256) void chunk_combine_kernel(
    float* __restrict__ Sc, const float* __restrict__ Pp) {
  const int bh = blockIdx.x;
  const int tid = threadIdx.x;
  for (int e = tid; e < HD * DSTATE; e += 256) {
    float hv = 0.f;
#pragma unroll
    for (int c = 0; c < NCH; c++) {
      const size_t idx = ((size_t)(bh * NCH + c)) * HD * DSTATE + e;
      const float sv = Sc[idx];
      Sc[idx] = hv;
      hv = hv * Pp[bh * NCH + c] + sv;
    }
  }
}

// ======== Pass C: Y = (CBt .* mask) @ X' + (C .* exp2(la)) @ h_in ============
__global__ __launch_bounds__(256) void ykernel(
    const float* __restrict__ CBt, const ushort_t* __restrict__ XpT,
    const ushort_t* __restrict__ xbcb, const float* __restrict__ Hc,
    const float* __restrict__ la2, float* __restrict__ y) {
  const int c = blockIdx.x, h = blockIdx.y, b = blockIdx.z;
  const int bc = b * NCH + c, bh = b * NH + h;
  const int row0 = b * LLEN + c * QCH;
  const int tid = threadIdx.x, lane = tid & 63, w = tid >> 6;
  __shared__ float laL[128], el[128];
  if (tid < 128) {
    const float v = la2[(size_t)(row0 + tid) * NH + h];
    laL[tid] = v; el[tid] = exp2f(v);
  }
  __syncthreads();
  const int wm = w * 32;
  const int fr = lane & 15, kk = (lane >> 4) * 8;
  const size_t xbase = ((size_t)bc * NH + h) * HD * 128;
  const float* hin = Hc + (size_t)(bh * NCH + c) * (HD * DSTATE);
  floatx4 acc[2][3];
#pragma unroll
  for (int i = 0; i < 2; i++)
#pragma unroll
    for (int j = 0; j < 3; j++) acc[i][j] = (floatx4){0.f, 0.f, 0.f, 0.f};

  // part 1: intra-chunk masked P @ X'
  for (int ki = 0; ki < 4; ki++) {
    const int kg = ki * 32 + kk;
    short8v a[2], bv[3];
#pragma unroll
    for (int mt = 0; mt < 2; mt++) {
      const int t = wm + mt * 16 + fr;
      const float lt = laL[t];
      const float* cb = &CBt[(size_t)(bc * 128 + t) * 128 + kg];
      const float4 u0 = *(const float4*)cb;
      const float4 u1 = *(const float4*)(cb + 4);
      const float f[8] = {u0.x, u0.y, u0.z, u0.w, u1.x, u1.y, u1.z, u1.w};
      short8v s;
#pragma unroll
      for (int e = 0; e < 8; e++) {
        const int sidx = kg + e;
        const float m = (t >= sidx) ? exp2f(lt - laL[sidx]) : 0.f;
        s[e] = (short)f2bf(f[e] * m);
      }
      a[mt] = s;
    }
#pragma unroll
    for (int nt = 0; nt < 3; nt++)
      bv[nt] = *(const short8v*)&XpT[xbase + (size_t)(nt * 16 + fr) * 128 + kg];
#pragma unroll
    for (int mt = 0; mt < 2; mt++)
#pragma unroll
      for (int nt = 0; nt < 3; nt++)
        acc[mt][nt] = __builtin_amdgcn_mfma_f32_16x16x32_bf16(
            a[mt], bv[nt], acc[mt][nt], 0, 0, 0);
  }
  // part 2: inter-chunk (C .* el) @ h_in ; C read directly from xbc_bf
  for (int ki = 0; ki < 4; ki++) {
    const int kg = ki * 32 + kk;
    short8v a[2], bv[3];
#pragma unroll
    for (int mt = 0; mt < 2; mt++) {
      const int t = wm + mt * 16 + fr;
      const float scl = el[t];
      const short8v raw = *(const short8v*)&xbcb[(size_t)(row0 + t) * CONVD +
                                                 DINNER + DSTATE + kg];
      short8v s;
#pragma unroll
      for (int e = 0; e < 8; e++) s[e] = (short)f2bf(bf2f(raw[e]) * scl);
      a[mt] = s;
    }
#pragma unroll
    for (int nt = 0; nt < 3; nt++) {
      const float* hp = &hin[(size_t)(nt * 16 + fr) * 128 + kg];
      const float4 u0 = *(const float4*)hp;
      const float4 u1 = *(const float4*)(hp + 4);
      const float f[8] = {u0.x, u0.y, u0.z, u0.w, u1.x, u1.y, u1.z, u1.w};
      short8v s;
#pragma unroll
      for (int e = 0; e < 8; e++) s[e] = (short)f2bf(f[e]);
      bv[nt] = s;
    }
#pragma unroll
    for (int mt = 0; mt < 2; mt++)
#pragma unroll
      for (int nt = 0; nt < 3; nt++)
        acc[mt][nt] = __builtin_amdgcn_mfma_f32_16x16x32_bf16(
            a[mt], bv[nt], acc[mt][nt], 0, 0, 0);
  }
  const int crow = (lane >> 4) * 4;
#pragma unroll
  for (int mt = 0; mt < 2; mt++)
#pragma unroll
    for (int nt = 0; nt < 3; nt++)
#pragma unroll
      for (int j = 0; j < 4; j++) {
        const int row = row0 + wm + mt * 16 + crow + j;
        y[(size_t)row * DINNER + h * HD + nt * 16 + fr] = acc[mt][nt][j];
      }
}

// ===== gate (silu(z)) + RMSNorm over 1536, bf16 inputs, emit bf16 ============
__global__ __launch_bounds__(256) void gate_rms_kernel(
    const ushort_t* __restrict__ zxb, const ushort_t* __restrict__ xbcb,
    const float* __restrict__ Dv, const float* __restrict__ rms_w,
    const float* __restrict__ y, ushort_t* __restrict__ ybf) {
  const int row = blockIdx.x;
  const int tid = threadIdx.x;
  __shared__ float sred[4];
  float g[8];
  float ss = 0.f;
  if (tid < 192) {
    const int e0 = tid * 8;
    const short8v xv = *(const short8v*)&xbcb[(size_t)row * CONVD + e0];
    const short8v zv = *(const short8v*)&zxb[(size_t)row * DPROJP + e0];
    const float4 y0 = *(const float4*)&y[(size_t)row * DINNER + e0];
    const float4 y1 = *(const float4*)&y[(size_t)row * DINNER + e0 + 4];
    const float yf[8] = {y0.x, y0.y, y0.z, y0.w, y1.x, y1.y, y1.z, y1.w};
#pragma unroll
    for (int j = 0; j < 8; j++) {
      const int e = e0 + j;
      const float yv = yf[j] + Dv[e / HD] * bf2f(xv[j]);
      const float z = bf2f(zv[j]);
      const float gv = yv * (z / (1.f + expf(-z)));
      g[j] = gv;
      ss += gv * gv;
    }
  } else {
#pragma unroll
    for (int j = 0; j < 8; j++) g[j] = 0.f;
  }
#pragma unroll
  for (int off = 32; off; off >>= 1) ss += __shfl_down(ss, off, 64);
  if ((tid & 63) == 0) sred[tid >> 6] = ss;
  __syncthreads();
  const float tot = sred[0] + sred[1] + sred[2] + sred[3];
  const float scale = rsqrtf(tot / DINNER + 1e-5f);
  if (tid < 192) {
    const int e0 = tid * 8;
    const float4 w0 = *(const float4*)&rms_w[e0];
    const float4 w1 = *(const float4*)&rms_w[e0 + 4];
    const float wf[8] = {w0.x, w0.y, w0.z, w0.w, w1.x, w1.y, w1.z, w1.w};
    short8v o;
#pragma unroll
    for (int j = 0; j < 8; j++) o[j] = (short)f2bf(g[j] * scale * wf[j]);
    *(short8v*)&ybf[(size_t)row * DINNER + e0] = o;
  }
}

// ================= residual + LayerNorm over 768 =============================
__global__ __launch_bounds__(256) void resid_ln_kernel(
    const float* __restrict__ go, const float* __restrict__ x,
    const float* __restrict__ ln_w, const float* __restrict__ ln_b,
    float* __restrict__ out) {
  const int row = blockIdx.x;
  const int tid = threadIdx.x;
  __shared__ float sred[4];
  __shared__ float sred2[4];
  float r[3];
  float s = 0.f;
#pragma unroll
  for (int i = 0; i < 3; i++) {
    const int e = tid + i * 256;
    r[i] = go[(size_t)row * DMODEL + e] + x[(size_t)row * DMODEL + e];
    s += r[i];
  }
#pragma unroll
  for (int off = 32; off; off >>= 1) s += __shfl_down(s, off, 64);
  if ((tid & 63) == 0) sred[tid >> 6] = s;
  __syncthreads();
  const float mu = (sred[0] + sred[1] + sred[2] + sred[3]) * (1.f / DMODEL);
  float s2 = 0.f;
#pragma unroll
  for (int i = 0; i < 3; i++) {
    const float d = r[i] - mu;
    s2 += d * d;
  }
#pragma unroll
  for (int off = 32; off; off >>= 1) s2 += __shfl_down(s2, off, 64);
  if ((tid & 63) == 0) sred2[tid >> 6] = s2;
  __syncthreads();
  const float var = (sred2[0] + sred2[1] + sred2[2] + sred2[3]) * (1.f / DMODEL);
  const float inv = rsqrtf(var + 1e-5f);
#pragma unroll
  for (int i = 0; i < 3; i++) {
    const int e = tid + i * 256;
    out[(size_t)row * DMODEL + e] = (r[i] - mu) * inv * ln_w[e] + ln_b[e];
  }
}

// ================= launch ====================================================
extern "C" void kernel_launch(void* const* d_in, const int* in_sizes, int n_in,
                              void* d_out, int out_size, void* d_ws, size_t ws_size,
                              hipStream_t stream) {
  const float* x          = (const float*)d_in[0];
  const float* in_proj_w  = (const float*)d_in[1];
  const float* conv_w     = (const float*)d_in[2];
  const float* conv_b     = (const float*)d_in[3];
  const float* dt_bias    = (const float*)d_in[4];
  const float* A_log      = (const float*)d_in[5];
  const float* Dv         = (const float*)d_in[6];
  const float* rms_w      = (const float*)d_in[7];
  const float* out_proj_w = (const float*)d_in[8];
  const float* ln_w       = (const float*)d_in[9];
  const float* ln_b       = (const float*)d_in[10];
  float* out = (float*)d_out;
  float* ws  = (float*)d_ws;

  ushort_t* zxb  = (ushort_t*)(ws + OFF_ZX);
  ushort_t* xbcb = (ushort_t*)(ws + OFF_XBC);
  float* dtb  = ws + OFF_DT;
  float* la2  = ws + OFF_LA;
  float* Sc   = ws + OFF_SC;
  float* ybuf = ws + OFF_Y;
  float* Pp   = ws + OFF_PP;
  float* CBt  = ws + OFF_CBT;
  ushort_t* BTbf = (ushort_t*)(ws + OFF_BTBF);
  ushort_t* XpT  = (ushort_t*)(ws + OFF_XPT);

  // aliased staging
  ushort_t* xbf   = (ushort_t*)(ws + OFF_Y);             // GEMM1 phase (ybuf dead)
  ushort_t* ipwbf = (ushort_t*)(ws + OFF_Y + 786432);
  ushort_t* ybf   = (ushort_t*)(ws + OFF_SC);            // GEMM2 phase (Sc dead)
  ushort_t* opwbf = (ushort_t*)(ws + OFF_SC + 1572864);
  float*    go    = ws + OFF_ZX;                         // GEMM2 out (zxb dead)

  // 0) convert x + in_proj_w (fused)
  convert_in_kernel<<<2064, 256, 0, stream>>>(x, in_proj_w, xbf, ipwbf);

  // 1) in_proj -> bf16 zx
  gemm_bf16_bfout<<<dim3(DPROJP / 128, ROWS / 128), 256, 0, stream>>>(
      xbf, ipwbf, zxb, ROWS, DPROJP, DMODEL);

  // 2) conv + silu + dt (bf16 in/out)
  conv_dt_kernel<<<ROWS, 256, 0, stream>>>(zxb, conv_w, conv_b, dt_bias, xbcb, dtb);

  // 3) chunked scan (matrix form)
  cumsum_kernel<<<dim3(NCH, NH, BDIM), 128, 0, stream>>>(dtb, A_log, la2, Pp);
  prep_bt_kernel<<<BDIM * NCH, 256, 0, stream>>>(xbcb, BTbf);
  prep_x_kernel<<<dim3(NCH, NH, BDIM), 256, 0, stream>>>(xbcb, dtb, XpT);
  cbt_kernel<<<BDIM * NCH, 256, 0, stream>>>(xbcb, CBt);
  stateA_kernel<<<dim3(NCH, NH, BDIM), 256, 0, stream>>>(XpT, BTbf, la2, Sc);
  chunk_combine_kernel<<<BDIM * NH, 256, 0, stream>>>(Sc, Pp);
  ykernel<<<dim3(NCH, NH, BDIM), 256, 0, stream>>>(CBt, XpT, xbcb, Sc, la2, ybuf);

  // 4) gate + RMSNorm -> bf16
  gate_rms_kernel<<<ROWS, 256, 0, stream>>>(zxb, xbcb, Dv, rms_w, ybuf, ybf);

  // 5) out_proj (192 blocks)
  convert_bf16_kernel<<<(DMODEL * DINNER / 8 + 255) / 256, 256, 0, stream>>>(
      out_proj_w, opwbf, DMODEL * DINNER / 8);
  gemm_bf16_n64<<<dim3(DMODEL / 64, ROWS / 128), 256, 0, stream>>>(
      ybf, opwbf, go, ROWS, DMODEL, DINNER);

  // 6) residual + LayerNorm
  resid_ln_kernel<<<ROWS, 256, 0, stream>>>(go, x, ln_w, ln_b, out);
}

// Round 9
// 210.027 us; speedup vs baseline: 3.3822x; 1.1161x over previous
//
#include <hip/hip_runtime.h>
#include <math.h>

#define BDIM 2
#define LLEN 1024
#define DMODEL 768
#define DINNER 1536
#define DSTATE 128
#define NH 32
#define HD 48
#define CONVD 1792
#define DPROJ 3360
#define DPROJP 3456
#define QCH 128
#define NCH 8
#define ROWS (BDIM*LLEN)

typedef unsigned short ushort_t;
typedef __attribute__((ext_vector_type(4))) short short4v;
typedef __attribute__((ext_vector_type(8))) short short8v;
typedef __attribute__((ext_vector_type(4))) float floatx4;

// ---- workspace layout (float units, no aliasing; total ~69 MB) ----
#define OFF_ZX   0ull          // zx_bf  u16 [2048][3456]
#define OFF_XBC  3538944ull    // xbc_bf u16 [2048][1792]
#define OFF_DT   5373952ull    // dt f32 [2048][32]
#define OFF_LA   5439488ull    // la2 f32 [2048][32]
#define OFF_SC   5505024ull    // Sc f32 [64][8][48][128]
#define OFF_Y    8650752ull    // y bf16 [2048][1536]
#define OFF_PP   10223616ull   // Pp f32 [512]
#define OFF_CBT  10224640ull   // CBt f32 [16][128][128]
#define OFF_BTBF 10486784ull   // BT bf16 [16][128][128]
#define OFF_XPT  10617856ull   // XpT bf16 [16][32][48][128]
#define OFF_XBF  12190720ull   // x bf16 [2048][768]
#define OFF_IPW  12977152ull   // ipw bf16 [3456][768]
#define OFF_OPW  14304256ull   // opw bf16 [768][1536]
#define OFF_YBF  14894080ull   // ybf bf16 [2048][1536]
#define OFF_GO   16466944ull   // go f32 [2048][768]

__device__ __forceinline__ ushort_t f2bf(float f) {
  union { float f; unsigned int u; } v; v.f = f;
  return (ushort_t)((v.u + 0x7FFFu + ((v.u >> 16) & 1u)) >> 16);
}
__device__ __forceinline__ float bf2f(short s) {
  union { unsigned int u; float f; } v; v.u = ((unsigned int)(ushort_t)s) << 16;
  return v.f;
}

#define GLOAD_LDS16(gptr, lptr) \
  __builtin_amdgcn_global_load_lds( \
      (const __attribute__((address_space(1))) void*)(gptr), \
      (__attribute__((address_space(3))) void*)(lptr), 16, 0, 0)

// ===== fused converts: [0,768) x ; [768,2064) ipw(+pad) ; [2064,2640) opw ====
__global__ __launch_bounds__(256) void convert_in_kernel(
    const float* __restrict__ x, const float* __restrict__ w,
    const float* __restrict__ opw, ushort_t* __restrict__ xbf,
    ushort_t* __restrict__ ipwbf, ushort_t* __restrict__ opwbf) {
  const int blk = blockIdx.x;
  if (blk < 768) {
    const int i = blk * 256 + threadIdx.x;
    const float4 a = ((const float4*)x)[i * 2];
    const float4 b = ((const float4*)x)[i * 2 + 1];
    short8v o;
    o[0] = (short)f2bf(a.x); o[1] = (short)f2bf(a.y);
    o[2] = (short)f2bf(a.z); o[3] = (short)f2bf(a.w);
    o[4] = (short)f2bf(b.x); o[5] = (short)f2bf(b.y);
    o[6] = (short)f2bf(b.z); o[7] = (short)f2bf(b.w);
    *(short8v*)(xbf + (size_t)i * 8) = o;
  } else if (blk < 2064) {
    const int i = (blk - 768) * 256 + threadIdx.x;  // 331,776 = 3456*96
    const int row = i / (DMODEL / 8);
    short8v o;
    if (row < DPROJ) {
      const float4 a = ((const float4*)w)[i * 2];
      const float4 b = ((const float4*)w)[i * 2 + 1];
      o[0] = (short)f2bf(a.x); o[1] = (short)f2bf(a.y);
      o[2] = (short)f2bf(a.z); o[3] = (short)f2bf(a.w);
      o[4] = (short)f2bf(b.x); o[5] = (short)f2bf(b.y);
      o[6] = (short)f2bf(b.z); o[7] = (short)f2bf(b.w);
    } else {
      for (int j = 0; j < 8; j++) o[j] = 0;
    }
    *(short8v*)(ipwbf + (size_t)i * 8) = o;
  } else {
    const int i = (blk - 2064) * 256 + threadIdx.x; // 147,456
    const float4 a = ((const float4*)opw)[i * 2];
    const float4 b = ((const float4*)opw)[i * 2 + 1];
    short8v o;
    o[0] = (short)f2bf(a.x); o[1] = (short)f2bf(a.y);
    o[2] = (short)f2bf(a.z); o[3] = (short)f2bf(a.w);
    o[4] = (short)f2bf(b.x); o[5] = (short)f2bf(b.y);
    o[6] = (short)f2bf(b.z); o[7] = (short)f2bf(b.w);
    *(short8v*)(opwbf + (size_t)i * 8) = o;
  }
}

// ============ bf16 MFMA GEMM, bf16 output (in_proj) ==========================
__global__ __launch_bounds__(256) void gemm_bf16_bfout(
    const ushort_t* __restrict__ A, const ushort_t* __restrict__ B,
    ushort_t* __restrict__ C, int M, int N, int K) {
  __shared__ __align__(16) ushort_t As[128 * 32];
  __shared__ __align__(16) ushort_t Bs[128 * 32];
  const int tid = threadIdx.x, lane = tid & 63, w = tid >> 6;
  const int wm = (w >> 1) * 64, wn = (w & 1) * 64;
  const int m0 = blockIdx.y * 128, n0 = blockIdx.x * 128;
  floatx4 acc[4][4];
#pragma unroll
  for (int i = 0; i < 4; i++)
#pragma unroll
    for (int j = 0; j < 4; j++) acc[i][j] = (floatx4){0.f, 0.f, 0.f, 0.f};
  const int srow = tid >> 2, skc = (tid & 3) * 8;
  const int kk = (lane >> 4) * 8, fr = lane & 15;
  for (int k0 = 0; k0 < K; k0 += 32) {
#pragma unroll
    for (int i = 0; i < 2; i++) {
      GLOAD_LDS16(A + (size_t)(m0 + i * 64 + srow) * K + k0 + skc,
                  As + (i * 64 + srow) * 32 + skc);
      GLOAD_LDS16(B + (size_t)(n0 + i * 64 + srow) * K + k0 + skc,
                  Bs + (i * 64 + srow) * 32 + skc);
    }
    __syncthreads();
    short8v a[4], bv[4];
#pragma unroll
    for (int mr = 0; mr < 4; mr++)
      a[mr] = *(const short8v*)(As + (wm + mr * 16 + fr) * 32 + kk);
#pragma unroll
    for (int nc = 0; nc < 4; nc++)
      bv[nc] = *(const short8v*)(Bs + (wn + nc * 16 + fr) * 32 + kk);
#pragma unroll
    for (int mr = 0; mr < 4; mr++)
#pragma unroll
      for (int nc = 0; nc < 4; nc++)
        acc[mr][nc] = __builtin_amdgcn_mfma_f32_16x16x32_bf16(
            a[mr], bv[nc], acc[mr][nc], 0, 0, 0);
    __syncthreads();
  }
  const int crow = (lane >> 4) * 4;
#pragma unroll
  for (int mr = 0; mr < 4; mr++)
#pragma unroll
    for (int nc = 0; nc < 4; nc++)
#pragma unroll
      for (int j = 0; j < 4; j++)
        C[(size_t)(m0 + wm + mr * 16 + crow + j) * N + n0 + wn + nc * 16 + fr] =
            f2bf(acc[mr][nc][j]);
}

// ============ bf16 MFMA GEMM, BN=64, fp32 out (out_proj) =====================
__global__ __launch_bounds__(256) void gemm_bf16_n64(
    const ushort_t* __restrict__ A, const ushort_t* __restrict__ B,
    float* __restrict__ C, int M, int N, int K) {
  __shared__ __align__(16) ushort_t As[128 * 32];
  __shared__ __align__(16) ushort_t Bs[64 * 32];
  const int tid = threadIdx.x, lane = tid & 63, w = tid >> 6;
  const int wm = (w >> 1) * 64, wn = (w & 1) * 32;
  const int m0 = blockIdx.y * 128, n0 = blockIdx.x * 64;
  floatx4 acc[4][2];
#pragma unroll
  for (int i = 0; i < 4; i++)
#pragma unroll
    for (int j = 0; j < 2; j++) acc[i][j] = (floatx4){0.f, 0.f, 0.f, 0.f};
  const int srow = tid >> 2, skc = (tid & 3) * 8;
  const int kk = (lane >> 4) * 8, fr = lane & 15;
  for (int k0 = 0; k0 < K; k0 += 32) {
#pragma unroll
    for (int i = 0; i < 2; i++)
      GLOAD_LDS16(A + (size_t)(m0 + i * 64 + srow) * K + k0 + skc,
                  As + (i * 64 + srow) * 32 + skc);
    GLOAD_LDS16(B + (size_t)(n0 + srow) * K + k0 + skc, Bs + srow * 32 + skc);
    __syncthreads();
    short8v a[4], bv[2];
#pragma unroll
    for (int mr = 0; mr < 4; mr++)
      a[mr] = *(const short8v*)(As + (wm + mr * 16 + fr) * 32 + kk);
#pragma unroll
    for (int nc = 0; nc < 2; nc++)
      bv[nc] = *(const short8v*)(Bs + (wn + nc * 16 + fr) * 32 + kk);
#pragma unroll
    for (int mr = 0; mr < 4; mr++)
#pragma unroll
      for (int nc = 0; nc < 2; nc++)
        acc[mr][nc] = __builtin_amdgcn_mfma_f32_16x16x32_bf16(
            a[mr], bv[nc], acc[mr][nc], 0, 0, 0);
    __syncthreads();
  }
  const int crow = (lane >> 4) * 4;
#pragma unroll
  for (int mr = 0; mr < 4; mr++)
#pragma unroll
    for (int nc = 0; nc < 2; nc++)
#pragma unroll
      for (int j = 0; j < 4; j++)
        C[(size_t)(m0 + wm + mr * 16 + crow + j) * N + n0 + wn + nc * 16 + fr] =
            acc[mr][nc][j];
}

// ================= conv1d + silu + dt (bf16 in / bf16 out) ===================
__global__ __launch_bounds__(256) void conv_dt_kernel(
    const ushort_t* __restrict__ zxb, const float* __restrict__ conv_w,
    const float* __restrict__ conv_b, const float* __restrict__ dt_bias,
    ushort_t* __restrict__ xbcb, float* __restrict__ dtbuf) {
  const int row = blockIdx.x;
  const int t = row % LLEN;
  const int tid = threadIdx.x;
  for (int g = tid; g < CONVD / 4; g += 256) {
    const int c = g * 4;
    const float4 cb = *(const float4*)&conv_b[c];
    float acc0 = cb.x, acc1 = cb.y, acc2 = cb.z, acc3 = cb.w;
    float4 cw[4];
#pragma unroll
    for (int j = 0; j < 4; j++) cw[j] = *(const float4*)&conv_w[(c + j) * 4];
#pragma unroll
    for (int k = 0; k < 4; k++) {
      if (t - 3 + k >= 0) {
        const short4v v = *(const short4v*)&zxb[(size_t)(row - 3 + k) * DPROJP + DINNER + c];
        acc0 += bf2f(v[0]) * ((const float*)&cw[0])[k];
        acc1 += bf2f(v[1]) * ((const float*)&cw[1])[k];
        acc2 += bf2f(v[2]) * ((const float*)&cw[2])[k];
        acc3 += bf2f(v[3]) * ((const float*)&cw[3])[k];
      }
    }
    short4v o;
    o[0] = (short)f2bf(acc0 / (1.f + expf(-acc0)));
    o[1] = (short)f2bf(acc1 / (1.f + expf(-acc1)));
    o[2] = (short)f2bf(acc2 / (1.f + expf(-acc2)));
    o[3] = (short)f2bf(acc3 / (1.f + expf(-acc3)));
    *(short4v*)&xbcb[(size_t)row * CONVD + c] = o;
  }
  if (tid < NH) {
    const float v = bf2f(zxb[(size_t)row * DPROJP + (DPROJ - NH) + tid]) + dt_bias[tid];
    dtbuf[row * NH + tid] = (v > 20.f) ? v : log1pf(expf(v));
  }
}

// ===== fused prep: [0,512) prep_x ; [512,528) prep_bt ; [528,1040) cumsum ====
__global__ __launch_bounds__(256) void prepfuse_kernel(
    const ushort_t* __restrict__ xbcb, const float* __restrict__ dtb,
    const float* __restrict__ A_log, ushort_t* __restrict__ XpT,
    ushort_t* __restrict__ BTbf, float* __restrict__ la2,
    float* __restrict__ Pp) {
  __shared__ ushort_t lb[128][136];
  __shared__ float dts[128];
  const int blk = blockIdx.x;
  const int tid = threadIdx.x;
  if (blk < 512) {
    // ---- prep_x: XpT[p][t] = bf16(x*dt) per (b,c,h)
    const int c = blk & 7, h = (blk >> 3) & 31, b = blk >> 8;
    const int row0 = b * LLEN + c * QCH;
    if (tid < 128) dts[tid] = dtb[(size_t)(row0 + tid) * NH + h];
    __syncthreads();
    for (int idx = tid; idx < 128 * 12; idx += 256) {
      const int r = idx / 12, f4 = (idx % 12) * 4;
      const short4v v = *(const short4v*)&xbcb[(size_t)(row0 + r) * CONVD + h * HD + f4];
      const float d = dts[r];
      short4v o;
      o[0] = (short)f2bf(bf2f(v[0]) * d); o[1] = (short)f2bf(bf2f(v[1]) * d);
      o[2] = (short)f2bf(bf2f(v[2]) * d); o[3] = (short)f2bf(bf2f(v[3]) * d);
      *(short4v*)&lb[r][f4] = o;
    }
    __syncthreads();
    const size_t base = ((size_t)(b * NCH + c) * NH + h) * HD * 128;
    for (int idx = tid; idx < 48 * 16; idx += 256) {
      const int p = idx % 48, t0 = (idx / 48) * 8;
      short8v o;
#pragma unroll
      for (int j = 0; j < 8; j++) o[j] = lb[t0 + j][p];
      *(short8v*)&XpT[base + (size_t)p * 128 + t0] = o;
    }
  } else if (blk < 528) {
    // ---- prep_bt: BT[n][t] per (b,c)
    const int bc = blk - 512;
    const int b = bc / NCH, c = bc % NCH;
    const int row0 = b * LLEN + c * QCH;
    for (int idx = tid; idx < 128 * 32; idx += 256) {
      const int t = idx >> 5, f4 = (idx & 31) * 4;
      const short4v v = *(const short4v*)&xbcb[(size_t)(row0 + t) * CONVD + DINNER + f4];
      *(short4v*)&lb[t][f4] = v;
    }
    __syncthreads();
    for (int idx = tid; idx < 128 * 16; idx += 256) {
      const int n = idx & 127, t0 = (idx >> 7) * 8;
      short8v o;
#pragma unroll
      for (int j = 0; j < 8; j++) o[j] = lb[t0 + j][n];
      *(short8v*)&BTbf[(size_t)(bc * 128 + n) * 128 + t0] = o;
    }
  } else {
    // ---- cumsum: la2 + Pp per (b,c,h); rows handled by tid<128
    const int idx = blk - 528;
    const int c = idx & 7, h = (idx >> 3) & 31, b = idx >> 8;
    const int lane = tid & 63;
    const int row = b * LLEN + c * QCH + tid;
    float v = 0.f;
    if (tid < 128) v = dtb[(size_t)row * NH + h];
#pragma unroll
    for (int off = 1; off < 64; off <<= 1) {
      const float u = __shfl_up(v, off, 64);
      if (lane >= off) v += u;
    }
    if (tid == 63) dts[0] = v;
    __syncthreads();
    if (tid >= 64 && tid < 128) v += dts[0];
    if (tid < 128) {
      const float la2v = -expf(A_log[h]) * v * 1.44269504088896f;
      la2[(size_t)row * NH + h] = la2v;
      if (tid == 127) Pp[(b * NH + h) * NCH + c] = exp2f(la2v);
    }
  }
}

// ===== fused: [0,512) stateA per (b,c,h) ; [512,528) cbt per (b,c) ===========
__global__ __launch_bounds__(256) void stateA_cbt_kernel(
    const ushort_t* __restrict__ XpT, const ushort_t* __restrict__ BTbf,
    const ushort_t* __restrict__ xbcb, const float* __restrict__ la2,
    float* __restrict__ Sc, float* __restrict__ CBt) {
  __shared__ float ew[128];
  const int blk = blockIdx.x;
  const int tid = threadIdx.x, lane = tid & 63, w = tid >> 6;
  const int fr = lane & 15, kk = (lane >> 4) * 8;
  if (blk < 512) {
    const int c = blk & 7, h = (blk >> 3) & 31, b = blk >> 8;
    const int bc = b * NCH + c, bh = b * NH + h;
    const int row0 = b * LLEN + c * QCH;
    const float laL = la2[(size_t)(row0 + 127) * NH + h];
    if (tid < 128) ew[tid] = exp2f(laL - la2[(size_t)(row0 + tid) * NH + h]);
    __syncthreads();
    const int wn = w * 32;
    const size_t xbase = ((size_t)bc * NH + h) * HD * 128;
    floatx4 acc[3][2];
#pragma unroll
    for (int i = 0; i < 3; i++)
#pragma unroll
      for (int j = 0; j < 2; j++) acc[i][j] = (floatx4){0.f, 0.f, 0.f, 0.f};
    for (int ki = 0; ki < 4; ki++) {
      const int kg = ki * 32 + kk;
      short8v a[3], bv[2];
#pragma unroll
      for (int mt = 0; mt < 3; mt++) {
        const short8v raw = *(const short8v*)&XpT[xbase + (size_t)(mt * 16 + fr) * 128 + kg];
        short8v s;
#pragma unroll
        for (int e = 0; e < 8; e++) s[e] = (short)f2bf(bf2f(raw[e]) * ew[kg + e]);
        a[mt] = s;
      }
#pragma unroll
      for (int nt = 0; nt < 2; nt++)
        bv[nt] = *(const short8v*)&BTbf[(size_t)(bc * 128 + wn + nt * 16 + fr) * 128 + kg];
#pragma unroll
      for (int mt = 0; mt < 3; mt++)
#pragma unroll
        for (int nt = 0; nt < 2; nt++)
          acc[mt][nt] = __builtin_amdgcn_mfma_f32_16x16x32_bf16(
              a[mt], bv[nt], acc[mt][nt], 0, 0, 0);
    }
    const int crow = (lane >> 4) * 4;
    float* sc = Sc + (size_t)(bh * NCH + c) * (HD * DSTATE);
#pragma unroll
    for (int mt = 0; mt < 3; mt++)
#pragma unroll
      for (int nt = 0; nt < 2; nt++)
#pragma unroll
        for (int j = 0; j < 4; j++)
          sc[(size_t)(mt * 16 + crow + j) * 128 + wn + nt * 16 + fr] = acc[mt][nt][j];
  } else {
    // ---- cbt: CBt[t][s] = C @ B^T read directly from xbc_bf
    const int bc = blk - 512;
    const int b = bc / NCH, c = bc % NCH;
    const int row0 = b * LLEN + c * QCH;
    const int wm = w * 32;
    floatx4 acc[2][8];
#pragma unroll
    for (int i = 0; i < 2; i++)
#pragma unroll
      for (int j = 0; j < 8; j++) acc[i][j] = (floatx4){0.f, 0.f, 0.f, 0.f};
    for (int ki = 0; ki < 4; ki++) {
      const int kg = ki * 32 + kk;
      short8v a[2], bv[8];
#pragma unroll
      for (int mt = 0; mt < 2; mt++)
        a[mt] = *(const short8v*)&xbcb[(size_t)(row0 + wm + mt * 16 + fr) * CONVD +
                                       DINNER + DSTATE + kg];
#pragma unroll
      for (int nt = 0; nt < 8; nt++)
        bv[nt] = *(const short8v*)&xbcb[(size_t)(row0 + nt * 16 + fr) * CONVD +
                                        DINNER + kg];
#pragma unroll
      for (int mt = 0; mt < 2; mt++)
#pragma unroll
        for (int nt = 0; nt < 8; nt++)
          acc[mt][nt] = __builtin_amdgcn_mfma_f32_16x16x32_bf16(
              a[mt], bv[nt], acc[mt][nt], 0, 0, 0);
    }
    const int crow = (lane >> 4) * 4;
#pragma unroll
    for (int mt = 0; mt < 2; mt++)
#pragma unroll
      for (int nt = 0; nt < 8; nt++)
#pragma unroll
        for (int j = 0; j < 4; j++)
          CBt[(size_t)(bc * 128 + wm + mt * 16 + crow + j) * 128 + nt * 16 + fr] =
              acc[mt][nt][j];
  }
}

// ===== Pass B: combine, widened to 512 blocks (8 slices per bh) ==============
__global__ __launch_bounds__(256) void chunk_combine_kernel(
    float* __restrict__ Sc, const float* __restrict__ Pp) {
  const int bh = blockIdx.x >> 3;
  const int slice = blockIdx.x & 7;
  const int tid = threadIdx.x;
  const int e0 = slice * 768;
  for (int e = e0 + tid; e < e0 + 768; e += 256) {
    float hv = 0.f;
#pragma unroll
    for (int c = 0; c < NCH; c++) {
      const size_t idx = ((size_t)(bh * NCH + c)) * HD * DSTATE + e;
      const float sv = Sc[idx];
      Sc[idx] = hv;
      hv = hv * Pp[bh * NCH + c] + sv;
    }
  }
}

// ======== Pass C: Y = (CBt .* mask) @ X' + (C .* exp2(la)) @ h_in -> bf16 ====
__global__ __launch_bounds__(256) void ykernel(
    const float* __restrict__ CBt, const ushort_t* __restrict__ XpT,
    const ushort_t* __restrict__ xbcb, const float* __restrict__ Hc,
    const float* __restrict__ la2, ushort_t* __restrict__ yb) {
  const int c = blockIdx.x, h = blockIdx.y, b = blockIdx.z;
  const int bc = b * NCH + c, bh = b * NH + h;
  const int row0 = b * LLEN + c * QCH;
  const int tid = threadIdx.x, lane = tid & 63, w = tid >> 6;
  __shared__ float laL[128], el[128];
  if (tid < 128) {
    const float v = la2[(size_t)(row0 + tid) * NH + h];
    laL[tid] = v; el[tid] = exp2f(v);
  }
  __syncthreads();
  const int wm = w * 32;
  const int fr = lane & 15, kk = (lane >> 4) * 8;
  const size_t xbase = ((size_t)bc * NH + h) * HD * 128;
  const float* hin = Hc + (size_t)(bh * NCH + c) * (HD * DSTATE);
  floatx4 acc[2][3];
#pragma unroll
  for (int i = 0; i < 2; i++)
#pragma unroll
    for (int j = 0; j < 3; j++) acc[i][j] = (floatx4){0.f, 0.f, 0.f, 0.f};

  for (int ki = 0; ki < 4; ki++) {
    const int kg = ki * 32 + kk;
    short8v a[2], bv[3];
#pragma unroll
    for (int mt = 0; mt < 2; mt++) {
      const int t = wm + mt * 16 + fr;
      const float lt = laL[t];
      const float* cb = &CBt[(size_t)(bc * 128 + t) * 128 + kg];
      const float4 u0 = *(const float4*)cb;
      const float4 u1 = *(const float4*)(cb + 4);
      const float f[8] = {u0.x, u0.y, u0.z, u0.w, u1.x, u1.y, u1.z, u1.w};
      short8v s;
#pragma unroll
      for (int e = 0; e < 8; e++) {
        const int sidx = kg + e;
        const float m = (t >= sidx) ? exp2f(lt - laL[sidx]) : 0.f;
        s[e] = (short)f2bf(f[e] * m);
      }
      a[mt] = s;
    }
#pragma unroll
    for (int nt = 0; nt < 3; nt++)
      bv[nt] = *(const short8v*)&XpT[xbase + (size_t)(nt * 16 + fr) * 128 + kg];
#pragma unroll
    for (int mt = 0; mt < 2; mt++)
#pragma unroll
      for (int nt = 0; nt < 3; nt++)
        acc[mt][nt] = __builtin_amdgcn_mfma_f32_16x16x32_bf16(
            a[mt], bv[nt], acc[mt][nt], 0, 0, 0);
  }
  for (int ki = 0; ki < 4; ki++) {
    const int kg = ki * 32 + kk;
    short8v a[2], bv[3];
#pragma unroll
    for (int mt = 0; mt < 2; mt++) {
      const int t = wm + mt * 16 + fr;
      const float scl = el[t];
      const short8v raw = *(const short8v*)&xbcb[(size_t)(row0 + t) * CONVD +
                                                 DINNER + DSTATE + kg];
      short8v s;
#pragma unroll
      for (int e = 0; e < 8; e++) s[e] = (short)f2bf(bf2f(raw[e]) * scl);
      a[mt] = s;
    }
#pragma unroll
    for (int nt = 0; nt < 3; nt++) {
      const float* hp = &hin[(size_t)(nt * 16 + fr) * 128 + kg];
      const float4 u0 = *(const float4*)hp;
      const float4 u1 = *(const float4*)(hp + 4);
      const float f[8] = {u0.x, u0.y, u0.z, u0.w, u1.x, u1.y, u1.z, u1.w};
      short8v s;
#pragma unroll
      for (int e = 0; e < 8; e++) s[e] = (short)f2bf(f[e]);
      bv[nt] = s;
    }
#pragma unroll
    for (int mt = 0; mt < 2; mt++)
#pragma unroll
      for (int nt = 0; nt < 3; nt++)
        acc[mt][nt] = __builtin_amdgcn_mfma_f32_16x16x32_bf16(
            a[mt], bv[nt], acc[mt][nt], 0, 0, 0);
  }
  const int crow = (lane >> 4) * 4;
#pragma unroll
  for (int mt = 0; mt < 2; mt++)
#pragma unroll
    for (int nt = 0; nt < 3; nt++)
#pragma unroll
      for (int j = 0; j < 4; j++) {
        const int row = row0 + wm + mt * 16 + crow + j;
        yb[(size_t)row * DINNER + h * HD + nt * 16 + fr] = f2bf(acc[mt][nt][j]);
      }
}

// ===== gate (silu(z)) + RMSNorm over 1536, all-bf16 in, bf16 out =============
__global__ __launch_bounds__(256) void gate_rms_kernel(
    const ushort_t* __restrict__ zxb, const ushort_t* __restrict__ xbcb,
    const float* __restrict__ Dv, const float* __restrict__ rms_w,
    const ushort_t* __restrict__ yb, ushort_t* __restrict__ ybf) {
  const int row = blockIdx.x;
  const int tid = threadIdx.x;
  __shared__ float sred[4];
  float g[8];
  float ss = 0.f;
  if (tid < 192) {
    const int e0 = tid * 8;
    const short8v xv = *(const short8v*)&xbcb[(size_t)row * CONVD + e0];
    const short8v zv = *(const short8v*)&zxb[(size_t)row * DPROJP + e0];
    const short8v yv = *(const short8v*)&yb[(size_t)row * DINNER + e0];
#pragma unroll
    for (int j = 0; j < 8; j++) {
      const int e = e0 + j;
      const float yf = bf2f(yv[j]) + Dv[e / HD] * bf2f(xv[j]);
      const float z = bf2f(zv[j]);
      const float gv = yf * (z / (1.f + expf(-z)));
      g[j] = gv;
      ss += gv * gv;
    }
  } else {
#pragma unroll
    for (int j = 0; j < 8; j++) g[j] = 0.f;
  }
#pragma unroll
  for (int off = 32; off; off >>= 1) ss += __shfl_down(ss, off, 64);
  if ((tid & 63) == 0) sred[tid >> 6] = ss;
  __syncthreads();
  const float tot = sred[0] + sred[1] + sred[2] + sred[3];
  const float scale = rsqrtf(tot / DINNER + 1e-5f);
  if (tid < 192) {
    const int e0 = tid * 8;
    const float4 w0 = *(const float4*)&rms_w[e0];
    const float4 w1 = *(const float4*)&rms_w[e0 + 4];
    const float wf[8] = {w0.x, w0.y, w0.z, w0.w, w1.x, w1.y, w1.z, w1.w};
    short8v o;
#pragma unroll
    for (int j = 0; j < 8; j++) o[j] = (short)f2bf(g[j] * scale * wf[j]);
    *(short8v*)&ybf[(size_t)row * DINNER + e0] = o;
  }
}

// ================= residual + LayerNorm over 768 =============================
__global__ __launch_bounds__(256) void resid_ln_kernel(
    const float* __restrict__ go, const float* __restrict__ x,
    const float* __restrict__ ln_w, const float* __restrict__ ln_b,
    float* __restrict__ out) {
  const int row = blockIdx.x;
  const int tid = threadIdx.x;
  __shared__ float sred[4];
  __shared__ float sred2[4];
  float r[3];
  float s = 0.f;
#pragma unroll
  for (int i = 0; i < 3; i++) {
    const int e = tid + i * 256;
    r[i] = go[(size_t)row * DMODEL + e] + x[(size_t)row * DMODEL + e];
    s += r[i];
  }
#pragma unroll
  for (int off = 32; off; off >>= 1) s += __shfl_down(s, off, 64);
  if ((tid & 63) == 0) sred[tid >> 6] = s;
  __syncthreads();
  const float mu = (sred[0] + sred[1] + sred[2] + sred[3]) * (1.f / DMODEL);
  float s2 = 0.f;
#pragma unroll
  for (int i = 0; i < 3; i++) {
    const float d = r[i] - mu;
    s2 += d * d;
  }
#pragma unroll
  for (int off = 32; off; off >>= 1) s2 += __shfl_down(s2, off, 64);
  if ((tid & 63) == 0) sred2[tid >> 6] = s2;
  __syncthreads();
  const float var = (sred2[0] + sred2[1] + sred2[2] + sred2[3]) * (1.f / DMODEL);
  const float inv = rsqrtf(var + 1e-5f);
#pragma unroll
  for (int i = 0; i < 3; i++) {
    const int e = tid + i * 256;
    out[(size_t)row * DMODEL + e] = (r[i] - mu) * inv * ln_w[e] + ln_b[e];
  }
}

// ================= launch ====================================================
extern "C" void kernel_launch(void* const* d_in, const int* in_sizes, int n_in,
                              void* d_out, int out_size, void* d_ws, size_t ws_size,
                              hipStream_t stream) {
  const float* x          = (const float*)d_in[0];
  const float* in_proj_w  = (const float*)d_in[1];
  const float* conv_w     = (const float*)d_in[2];
  const float* conv_b     = (const float*)d_in[3];
  const float* dt_bias    = (const float*)d_in[4];
  const float* A_log      = (const float*)d_in[5];
  const float* Dv         = (const float*)d_in[6];
  const float* rms_w      = (const float*)d_in[7];
  const float* out_proj_w = (const float*)d_in[8];
  const float* ln_w       = (const float*)d_in[9];
  const float* ln_b       = (const float*)d_in[10];
  float* out = (float*)d_out;
  float* ws  = (float*)d_ws;

  ushort_t* zxb   = (ushort_t*)(ws + OFF_ZX);
  ushort_t* xbcb  = (ushort_t*)(ws + OFF_XBC);
  float* dtb  = ws + OFF_DT;
  float* la2  = ws + OFF_LA;
  float* Sc   = ws + OFF_SC;
  ushort_t* ybuf = (ushort_t*)(ws + OFF_Y);
  float* Pp   = ws + OFF_PP;
  float* CBt  = ws + OFF_CBT;
  ushort_t* BTbf  = (ushort_t*)(ws + OFF_BTBF);
  ushort_t* XpT   = (ushort_t*)(ws + OFF_XPT);
  ushort_t* xbf   = (ushort_t*)(ws + OFF_XBF);
  ushort_t* ipwbf = (ushort_t*)(ws + OFF_IPW);
  ushort_t* opwbf = (ushort_t*)(ws + OFF_OPW);
  ushort_t* ybf   = (ushort_t*)(ws + OFF_YBF);
  float*    go    = ws + OFF_GO;

  // 1) all input converts (x, in_proj_w padded, out_proj_w)
  convert_in_kernel<<<2640, 256, 0, stream>>>(x, in_proj_w, out_proj_w,
                                              xbf, ipwbf, opwbf);
  // 2) in_proj -> bf16 zx
  gemm_bf16_bfout<<<dim3(DPROJP / 128, ROWS / 128), 256, 0, stream>>>(
      xbf, ipwbf, zxb, ROWS, DPROJP, DMODEL);
  // 3) conv + silu + dt
  conv_dt_kernel<<<ROWS, 256, 0, stream>>>(zxb, conv_w, conv_b, dt_bias, xbcb, dtb);
  // 4) fused preps (prep_x | prep_bt | cumsum)
  prepfuse_kernel<<<1040, 256, 0, stream>>>(xbcb, dtb, A_log, XpT, BTbf, la2, Pp);
  // 5) fused stateA | cbt
  stateA_cbt_kernel<<<528, 256, 0, stream>>>(XpT, BTbf, xbcb, la2, Sc, CBt);
  // 6) chunk combine (widened)
  chunk_combine_kernel<<<512, 256, 0, stream>>>(Sc, Pp);
  // 7) y emission -> bf16
  ykernel<<<dim3(NCH, NH, BDIM), 256, 0, stream>>>(CBt, XpT, xbcb, Sc, la2, ybuf);
  // 8) gate + RMSNorm -> bf16
  gate_rms_kernel<<<ROWS, 256, 0, stream>>>(zxb, xbcb, Dv, rms_w, ybuf, ybf);
  // 9) out_proj
  gemm_bf16_n64<<<dim3(DMODEL / 64, ROWS / 128), 256, 0, stream>>>(
      ybf, opwbf, go, ROWS, DMODEL, DINNER);
  // 10) residual + LayerNorm
  resid_ln_kernel<<<ROWS, 256, 0, stream>>>(go, x, ln_w, ln_b, out);
}